// Round 13
// baseline (1758.889 us; speedup 1.0000x reference)
//
#include <hip/hip_runtime.h>
#include <cstddef>
#include <cstdint>

#define NB 8
#define NPTS 4096
#define NS 1024
#define NK 32
#define ND 64

typedef __attribute__((ext_vector_type(2))) float f32x2;

// ------------------------------------------------------------------
// fps+pgemm hetero kernel, 64-thread blocks.
// Blocks 0..7: SINGLE-WAVE FPS — no barrier, no cross-wave exchange.
// Lane L owns points [64L,64L+64) as 32 float2 (packed-f32 VALU ops,
// each component correctly rounded -> bit-exact vs scalar numpy order).
// Per iter: pk dist update -> scalar max tree -> 6-step DPP max ->
// ballot first lane -> j-scan (ascending, first occurrence) -> shfl
// widx -> LDS coord lookup (in-wave lgkmcnt ordering, no barrier).
// Blocks 8..519: pgemm (64 thr, 8x8 register tiles) hidden under fps.
// ------------------------------------------------------------------
#define DPP_IMAX(v, ctrl)                                                     \
  {                                                                           \
    int _o = __builtin_amdgcn_update_dpp(v, v, ctrl, 0xf, 0xf, false);        \
    v = (_o > v) ? _o : v;                                                    \
  }

// group-of-8 sum via row_shr (lanes 7 mod 8 hold their group's sum)
#define DPP_FADD(v, ctrl)                                                     \
  {                                                                           \
    int _t = __builtin_amdgcn_update_dpp(__float_as_int(v), __float_as_int(v),\
                                         ctrl, 0xf, 0xf, false);              \
    v = v + __int_as_float(_t);                                               \
  }

__global__ __launch_bounds__(64, 1) void fps_pgemm_kernel(
    const float* __restrict__ xyz, float* __restrict__ out_newxyz,
    float* __restrict__ ws_newxyz, const float* __restrict__ points,
    const float* __restrict__ W0, const float* __restrict__ b0g,
    float* __restrict__ P1) {
  __shared__ __align__(16) char smem[49152];
  const int t = threadIdx.x;  // 0..63

  if (blockIdx.x < 8) {
    // ---------------- single-wave FPS ----------------
    float* sX3 = (float*)smem;  // 4096 * 3 floats = 48 KB
    const int b = blockIdx.x;
    const int lane = t;
    const float* xb = xyz + (size_t)b * 3 * NPTS;

    // stage coord table (in-wave: no barrier needed before reads)
    for (int i = t; i < NPTS; i += 64) {
      sX3[i * 3 + 0] = xb[i];
      sX3[i * 3 + 1] = xb[NPTS + i];
      sX3[i * 3 + 2] = xb[2 * NPTS + i];
    }

    f32x2 px[32], py[32], pz[32], dd[32];
#pragma unroll
    for (int q = 0; q < 16; ++q) {
      float4 a = ((const float4*)xb)[lane * 16 + q];
      float4 bq = ((const float4*)(xb + NPTS))[lane * 16 + q];
      float4 c = ((const float4*)(xb + 2 * NPTS))[lane * 16 + q];
      px[2 * q] = (f32x2){a.x, a.y};
      px[2 * q + 1] = (f32x2){a.z, a.w};
      py[2 * q] = (f32x2){bq.x, bq.y};
      py[2 * q + 1] = (f32x2){bq.z, bq.w};
      pz[2 * q] = (f32x2){c.x, c.y};
      pz[2 * q + 1] = (f32x2){c.z, c.w};
    }
#pragma unroll
    for (int j = 0; j < 32; ++j) dd[j] = (f32x2){1e10f, 1e10f};

    float cx = xb[0], cy = xb[NPTS], cz = xb[2 * NPTS];  // centroid 0

    for (int s = 0; s < NS; ++s) {
      if (lane == 0) {
        out_newxyz[b * 3 * NS + s] = cx;
        out_newxyz[b * 3 * NS + NS + s] = cy;
        out_newxyz[b * 3 * NS + 2 * NS + s] = cz;
        ws_newxyz[((b << 10) + s) * 3 + 0] = cx;
        ws_newxyz[((b << 10) + s) * 3 + 1] = cy;
        ws_newxyz[((b << 10) + s) * 3 + 2] = cz;
      }
      const f32x2 c2x = (f32x2){cx, cx};
      const f32x2 c2y = (f32x2){cy, cy};
      const f32x2 c2z = (f32x2){cz, cz};
      // packed dist update: every component correctly rounded, same op
      // order as numpy ((dx*dx + dy*dy) + dz*dz), min = fmin
#pragma unroll
      for (int j = 0; j < 32; ++j) {
        f32x2 dx = px[j] - c2x;
        f32x2 dy = py[j] - c2y;
        f32x2 dz = pz[j] - c2z;
        f32x2 d = (dx * dx + dy * dy) + dz * dz;
        dd[j] = __builtin_elementwise_min(dd[j], d);
      }
      // scalar max tree over 64 components
      f32x2 r16[16];
#pragma unroll
      for (int i = 0; i < 16; ++i)
        r16[i] = __builtin_elementwise_max(dd[2 * i], dd[2 * i + 1]);
#pragma unroll
      for (int i = 0; i < 8; ++i)
        r16[i] = __builtin_elementwise_max(r16[2 * i], r16[2 * i + 1]);
#pragma unroll
      for (int i = 0; i < 4; ++i)
        r16[i] = __builtin_elementwise_max(r16[2 * i], r16[2 * i + 1]);
      f32x2 ra = __builtin_elementwise_max(r16[0], r16[1]);
      f32x2 rb = __builtin_elementwise_max(r16[2], r16[3]);
      f32x2 rr = __builtin_elementwise_max(ra, rb);
      float m = fmaxf(rr.x, rr.y);
      // wave max (nonneg floats: int order == float order)
      int v = __float_as_int(m);
      DPP_IMAX(v, 0x111)
      DPP_IMAX(v, 0x112)
      DPP_IMAX(v, 0x114)
      DPP_IMAX(v, 0x118)
      DPP_IMAX(v, 0x142)
      DPP_IMAX(v, 0x143)
      const int wm_i = __builtin_amdgcn_readlane(v, 63);
      const float wm = __int_as_float(wm_i);
      unsigned long long claim = __ballot(m == wm);
      int firstlane = __ffsll(claim) - 1;
      // every lane scans its own 64 dists for the smallest matching j
      int j = 63;
#pragma unroll
      for (int jj = 31; jj >= 0; --jj) {
        if (dd[jj].y == wm) j = 2 * jj + 1;
        if (dd[jj].x == wm) j = 2 * jj;
      }
      const int widx = __shfl(lane * 64 + j, firstlane);
      cx = sX3[widx * 3 + 0];
      cy = sX3[widx * 3 + 1];
      cz = sX3[widx * 3 + 2];
    }
  } else {
    // ---------------- pgemm: P1[b][n][o] = points·W0[:,3:] + b0 ----------
    float* sP = (float*)smem;            // 16384 B  [c][n]
    float* sW = (float*)(smem + 16384);  // 17408 B  [c][o] pitch 68
    float* sB = (float*)(smem + 33792);  // 256 B
    const int blk = blockIdx.x - 8;      // 0..511
    const int bb = blk >> 6;
    const int n0 = (blk & 63) * 64;
    const float* pb = points + (size_t)bb * ND * NPTS;
    for (int f = t; f < 4096; f += 64) {
      int c = f >> 6, n = f & 63;
      sP[f] = pb[c * NPTS + n0 + n];
    }
    for (int f = t; f < 4096; f += 64) {
      int c = f >> 6, o = f & 63;
      sW[c * 68 + o] = W0[o * 67 + 3 + c];
    }
    sB[t] = b0g[t];
    // single wave: in-order LDS ops, no barrier needed
    const int nl = (t & 7) * 8;
    const int ol = (t >> 3) * 8;
    float acc[8][8];
#pragma unroll
    for (int i = 0; i < 8; ++i)
#pragma unroll
      for (int j = 0; j < 8; ++j) acc[i][j] = 0.f;
#pragma unroll 2
    for (int c = 0; c < 64; ++c) {
      float4 x0 = *(const float4*)(sP + c * 64 + nl);
      float4 x1 = *(const float4*)(sP + c * 64 + nl + 4);
      float4 w0 = *(const float4*)(sW + c * 68 + ol);
      float4 w1 = *(const float4*)(sW + c * 68 + ol + 4);
      float xa[8] = {x0.x, x0.y, x0.z, x0.w, x1.x, x1.y, x1.z, x1.w};
      float wa[8] = {w0.x, w0.y, w0.z, w0.w, w1.x, w1.y, w1.z, w1.w};
#pragma unroll
      for (int i = 0; i < 8; ++i)
#pragma unroll
        for (int j = 0; j < 8; ++j) acc[i][j] += xa[i] * wa[j];
    }
#pragma unroll
    for (int i = 0; i < 8; ++i) {
      float4 v0 = make_float4(acc[i][0] + sB[ol + 0], acc[i][1] + sB[ol + 1],
                              acc[i][2] + sB[ol + 2], acc[i][3] + sB[ol + 3]);
      float4 v1 = make_float4(acc[i][4] + sB[ol + 4], acc[i][5] + sB[ol + 5],
                              acc[i][6] + sB[ol + 6], acc[i][7] + sB[ol + 7]);
      float* dst = P1 + ((size_t)(bb << 12) + n0 + nl + i) * 64 + ol;
      *(float4*)dst = v0;
      *(float4*)(dst + 4) = v1;
    }
  }
}

// ------------------------------------------------------------------
// Ball query + layer-0 gather stats fused (unchanged from R12)
// ------------------------------------------------------------------
__global__ __launch_bounds__(256) void query_gstats_kernel(
    const float* __restrict__ xyz, const float* __restrict__ ws_newxyz,
    const float* __restrict__ P1, const float* __restrict__ W0,
    int* __restrict__ idx_ws, float* __restrict__ partials) {
  const int w = threadIdx.x >> 6;
  const int lane = threadIdx.x & 63;
  const int p = blockIdx.x * 4 + w;  // 8192 pairs
  const int b = p >> 10;
  __shared__ int sIdx[4][32];
  __shared__ float sWS[4][64];
  __shared__ float sWQ[4][64];
  const float* xb = xyz + (size_t)b * 3 * NPTS;
  const float cx = ws_newxyz[p * 3 + 0];
  const float cy = ws_newxyz[p * 3 + 1];
  const float cz = ws_newxyz[p * 3 + 2];
  const float ss = __fadd_rn(__fadd_rn(__fmul_rn(cx, cx), __fmul_rn(cy, cy)), __fmul_rn(cz, cz));
  const float r2 = (float)(0.4 * 0.4);
  int cnt = 0;
  for (int ci = 0; ci < 64 && cnt < 32; ++ci) {
    int n = ci * 64 + lane;
    float x = xb[n], y = xb[NPTS + n], z = xb[2 * NPTS + n];
    float dot = __fadd_rn(__fadd_rn(__fmul_rn(cx, x), __fmul_rn(cy, y)), __fmul_rn(cz, z));
    float dd = __fadd_rn(__fadd_rn(__fmul_rn(x, x), __fmul_rn(y, y)), __fmul_rn(z, z));
    float d = __fmul_rn(-2.0f, dot);
    d = __fadd_rn(d, ss);
    d = __fadd_rn(d, dd);
    d = fmaxf(d, 1e-12f);  // clip
    bool inc = (d <= r2);
    unsigned long long m = __ballot(inc);
    int slot = cnt + (int)__popcll(m & ((1ull << lane) - 1ull));
    if (inc && slot < 32) sIdx[w][slot] = n;
    cnt += (int)__popcll(m);
  }
  if (lane < 32) {
    int v;
    if (lane < cnt) v = sIdx[w][lane];
    else v = (cnt > 0) ? sIdx[w][0] : 0;
    idx_ws[p * 32 + lane] = v;
    sIdx[w][lane] = v;
  }
  const float wx = W0[lane * 67 + 0];
  const float wy = W0[lane * 67 + 1];
  const float wz = W0[lane * 67 + 2];
  float ssum = 0.f, ssq = 0.f;
  for (int r = 0; r < 32; ++r) {
    const int n = sIdx[w][r];
    float P1v = P1[((size_t)(b << 12) + n) * 64 + lane];
    float dx = __fadd_rn(xb[n], -cx);
    float dy = __fadd_rn(xb[NPTS + n], -cy);
    float dz = __fadd_rn(xb[2 * NPTS + n], -cz);
    float y = P1v + (dx * wx + dy * wy + dz * wz);
    ssum += y;
    ssq += y * y;
  }
  sWS[w][lane] = ssum;
  sWQ[w][lane] = ssq;
  __syncthreads();
  const int t = threadIdx.x;
  if (t < 64) {
    float s1 = sWS[0][t] + sWS[1][t] + sWS[2][t] + sWS[3][t];
    float s2 = sWQ[0][t] + sWQ[1][t] + sWQ[2][t] + sWQ[3][t];
    partials[(size_t)blockIdx.x * 128 + t] = s1;
    partials[(size_t)blockIdx.x * 128 + 64 + t] = s2;
  }
}

// ------------------------------------------------------------------
// conv1 with gather-recompute staging (unchanged from R12)
// ------------------------------------------------------------------
__global__ __launch_bounds__(256) void conv1_kernel(
    const float* __restrict__ xyz, const float* __restrict__ P1,
    const int* __restrict__ idx_ws, const float* __restrict__ cen_ws,
    const float* __restrict__ W0, const float* __restrict__ W1,
    const float* __restrict__ bias, const float* __restrict__ scaleA,
    const float* __restrict__ shiftA, float* __restrict__ y1,
    float* __restrict__ partials) {
  constexpr int CIN = 64, COUT = 64, WP = 68, TPS = 128;
  __shared__ __align__(16) float sW[CIN * WP];
  __shared__ __align__(16) float sX[2 * CIN * 32];
  __shared__ float sY[64 * 65];
  __shared__ int sIdx[64];
  __shared__ float sCen[2 * 4];
  __shared__ float sScale[CIN];
  __shared__ float sShift[CIN];
  __shared__ float sSum[COUT];
  __shared__ float sSq[COUT];

  const int t = threadIdx.x;
  const int wave = t >> 6, lane = t & 63;
  const int pair0 = blockIdx.x * 2;
  const int b = pair0 >> 10;

  for (int f = t; f < CIN * COUT; f += 256) {
    int o = f / CIN;
    int c = f - o * CIN;
    sW[c * WP + o] = W1[f];
  }
  if (t < CIN) { sScale[t] = scaleA[t]; sShift[t] = shiftA[t]; }
  if (t < COUT) { sSum[t] = 0.f; sSq[t] = 0.f; }
  if (t < 64) sIdx[t] = idx_ws[pair0 * 32 + t];
  if (t < 6) sCen[(t / 3) * 4 + (t % 3)] = cen_ws[pair0 * 3 + t];
  const float wx = W0[lane * 67 + 0];
  const float wy = W0[lane * 67 + 1];
  const float wz = W0[lane * 67 + 2];
  __syncthreads();
  const float* xb = xyz + (size_t)b * 3 * NPTS;
  for (int r = wave; r < 64; r += 4) {
    const int sl = r >> 5;
    const int n = sIdx[r];
    float P1v = P1[((size_t)(b << 12) + n) * 64 + lane];
    float dx = __fadd_rn(xb[n], -sCen[sl * 4 + 0]);
    float dy = __fadd_rn(xb[NPTS + n], -sCen[sl * 4 + 1]);
    float dz = __fadd_rn(xb[2 * NPTS + n], -sCen[sl * 4 + 2]);
    sY[r * 65 + lane] = P1v + (dx * wx + dy * wy + dz * wz);
  }
  __syncthreads();
  for (int f = t; f < 2 * CIN * 32; f += 256) {
    int sl = f >> 11;
    int rmd = f & 2047;
    int o = rmd >> 5, k = rmd & 31;
    float v = sY[(sl * 32 + k) * 65 + o];
    v = v * sScale[o] + sShift[o];
    sX[f] = fmaxf(v, 0.f);
  }
  __syncthreads();

  const int sl = t / TPS;
  const int tl = t - sl * TPS;
  const int k0 = (tl & 7) * 4;
  const int o0 = (tl >> 3) * 4;

  float acc[4][4];
#pragma unroll
  for (int i = 0; i < 4; ++i)
#pragma unroll
    for (int j = 0; j < 4; ++j) acc[i][j] = 0.f;

  const float* xrow = sX + sl * (CIN * 32);
#pragma unroll 4
  for (int c = 0; c < CIN; ++c) {
    float4 xv = *(const float4*)(xrow + c * 32 + k0);
    float4 wv = *(const float4*)(sW + c * WP + o0);
    float xa[4] = {xv.x, xv.y, xv.z, xv.w};
    float wa[4] = {wv.x, wv.y, wv.z, wv.w};
#pragma unroll
    for (int i = 0; i < 4; ++i)
#pragma unroll
      for (int j = 0; j < 4; ++j) acc[i][j] += wa[i] * xa[j];
  }
#pragma unroll
  for (int i = 0; i < 4; ++i) {
    float bo = bias[o0 + i];
#pragma unroll
    for (int j = 0; j < 4; ++j) acc[i][j] += bo;
  }
#pragma unroll
  for (int i = 0; i < 4; ++i) {
    float s1 = (acc[i][0] + acc[i][1]) + (acc[i][2] + acc[i][3]);
    float s2 = (acc[i][0] * acc[i][0] + acc[i][1] * acc[i][1]) +
               (acc[i][2] * acc[i][2] + acc[i][3] * acc[i][3]);
    DPP_FADD(s1, 0x111)
    DPP_FADD(s1, 0x112)
    DPP_FADD(s1, 0x114)
    DPP_FADD(s2, 0x111)
    DPP_FADD(s2, 0x112)
    DPP_FADD(s2, 0x114)
    if ((t & 7) == 7) {
      atomicAdd(&sSum[o0 + i], s1);
      atomicAdd(&sSq[o0 + i], s2);
    }
  }
#pragma unroll
  for (int i = 0; i < 4; ++i) {
    float4 v = make_float4(acc[i][0], acc[i][1], acc[i][2], acc[i][3]);
    *(float4*)(y1 + (size_t)(pair0 + sl) * COUT * 32 + (o0 + i) * 32 + k0) = v;
  }
  __syncthreads();
  if (t < COUT) {
    partials[(size_t)blockIdx.x * (COUT * 2) + t] = sSum[t];
    partials[(size_t)blockIdx.x * (COUT * 2) + COUT + t] = sSq[t];
  }
}

// ------------------------------------------------------------------
// conv2 (MODE 2, unchanged from R12)
// ------------------------------------------------------------------
template <int CIN, int COUT, int SPB, int MODE>
__global__ __launch_bounds__(256) void conv_kernel(
    const float* __restrict__ xin, const float* __restrict__ W,
    const float* __restrict__ bias, const float* __restrict__ scaleA,
    const float* __restrict__ shiftA, float* __restrict__ yout,
    float* __restrict__ pmax, float* __restrict__ pmin,
    float* __restrict__ partials) {
  constexpr int WP = COUT + 4;
  constexpr int TPS = (COUT / 4) * 8;
  __shared__ __align__(16) float sW[CIN * WP];
  __shared__ __align__(16) float sX[SPB * CIN * 32];
  __shared__ float sScale[CIN];
  __shared__ float sShift[CIN];
  __shared__ float sSum[COUT];
  __shared__ float sSq[COUT];
  __shared__ float sMax[8 * COUT];
  __shared__ float sMin[8 * COUT];

  const int t = threadIdx.x;
  const int pair0 = blockIdx.x * SPB;

  for (int f = t; f < CIN * COUT; f += 256) {
    int o = f / CIN;
    int c = f - o * CIN;
    sW[c * WP + o] = W[f];
  }
  if (t < CIN) { sScale[t] = scaleA[t]; sShift[t] = shiftA[t]; }
  if (t < COUT) { sSum[t] = 0.f; sSq[t] = 0.f; }
  __syncthreads();

  for (int f = t; f < SPB * CIN * 32; f += 256) {
    int c = (f >> 5) % CIN;
    float v = xin[(size_t)pair0 * CIN * 32 + f];
    v = v * sScale[c] + sShift[c];
    sX[f] = fmaxf(v, 0.f);
  }
  __syncthreads();

  const int sl = t / TPS;
  const int tl = t - sl * TPS;
  const int k0 = (tl & 7) * 4;
  const int o0 = (tl >> 3) * 4;

  float acc[4][4];
#pragma unroll
  for (int i = 0; i < 4; ++i)
#pragma unroll
    for (int j = 0; j < 4; ++j) acc[i][j] = 0.f;

  const float* xrow = sX + sl * (CIN * 32);
#pragma unroll 4
  for (int c = 0; c < CIN; ++c) {
    float4 xv = *(const float4*)(xrow + c * 32 + k0);
    float4 wv = *(const float4*)(sW + c * WP + o0);
    float xa[4] = {xv.x, xv.y, xv.z, xv.w};
    float wa[4] = {wv.x, wv.y, wv.z, wv.w};
#pragma unroll
    for (int i = 0; i < 4; ++i)
#pragma unroll
      for (int j = 0; j < 4; ++j) acc[i][j] += wa[i] * xa[j];
  }
#pragma unroll
  for (int i = 0; i < 4; ++i) {
    float bo = bias[o0 + i];
#pragma unroll
    for (int j = 0; j < 4; ++j) acc[i][j] += bo;
  }
#pragma unroll
  for (int i = 0; i < 4; ++i) {
    float s1 = (acc[i][0] + acc[i][1]) + (acc[i][2] + acc[i][3]);
    float s2 = (acc[i][0] * acc[i][0] + acc[i][1] * acc[i][1]) +
               (acc[i][2] * acc[i][2] + acc[i][3] * acc[i][3]);
    DPP_FADD(s1, 0x111)
    DPP_FADD(s1, 0x112)
    DPP_FADD(s1, 0x114)
    DPP_FADD(s2, 0x111)
    DPP_FADD(s2, 0x112)
    DPP_FADD(s2, 0x114)
    if ((t & 7) == 7) {
      atomicAdd(&sSum[o0 + i], s1);
      atomicAdd(&sSq[o0 + i], s2);
    }
  }
  if (MODE < 2) {
#pragma unroll
    for (int i = 0; i < 4; ++i) {
      float4 v = make_float4(acc[i][0], acc[i][1], acc[i][2], acc[i][3]);
      *(float4*)(yout + (size_t)(pair0 + sl) * COUT * 32 + (o0 + i) * 32 + k0) = v;
    }
  } else {
#pragma unroll
    for (int i = 0; i < 4; ++i) {
      float mx = fmaxf(fmaxf(acc[i][0], acc[i][1]), fmaxf(acc[i][2], acc[i][3]));
      float mn = fminf(fminf(acc[i][0], acc[i][1]), fminf(acc[i][2], acc[i][3]));
      sMax[(k0 >> 2) * COUT + o0 + i] = mx;
      sMin[(k0 >> 2) * COUT + o0 + i] = mn;
    }
  }
  __syncthreads();
  if (t < COUT) {
    partials[(size_t)blockIdx.x * (COUT * 2) + t] = sSum[t];
    partials[(size_t)blockIdx.x * (COUT * 2) + COUT + t] = sSq[t];
    if (MODE == 2) {
      float mx = sMax[t];
      float mn = sMin[t];
#pragma unroll
      for (int q = 1; q < 8; ++q) {
        mx = fmaxf(mx, sMax[q * COUT + t]);
        mn = fminf(mn, sMin[q * COUT + t]);
      }
      pmax[pair0 * COUT + t] = mx;
      pmin[pair0 * COUT + t] = mn;
    }
  }
}

// one block per channel: f64 reduce -> fused scale/shift for next layer
template <int COUT>
__global__ __launch_bounds__(256) void stats_kernel(const float* __restrict__ partials,
                                                    int nblocks,
                                                    const float* __restrict__ gA,
                                                    const float* __restrict__ btA,
                                                    float* __restrict__ scaleA,
                                                    float* __restrict__ shiftA) {
  const int o = blockIdx.x;
  const int t = threadIdx.x;
  double s1 = 0.0, s2 = 0.0;
  for (int blk = t; blk < nblocks; blk += 256) {
    s1 += (double)partials[(size_t)blk * (COUT * 2) + o];
    s2 += (double)partials[(size_t)blk * (COUT * 2) + COUT + o];
  }
  __shared__ double r1[256], r2[256];
  r1[t] = s1; r2[t] = s2;
  __syncthreads();
  for (int st = 128; st > 0; st >>= 1) {
    if (t < st) { r1[t] += r1[t + st]; r2[t] += r2[t + st]; }
    __syncthreads();
  }
  if (t == 0) {
    const double Nr = 262144.0;  // B*K*S
    double mean = r1[0] / Nr;
    double var = r2[0] / Nr - mean * mean;
    double rstd = 1.0 / sqrt(var + 1e-5);
    double sc = rstd * (double)gA[o];
    scaleA[o] = (float)sc;
    shiftA[o] = (float)((double)btA[o] - mean * sc);
  }
}

// layer-2 stats + final normalize fused: one block per channel (128).
__global__ __launch_bounds__(256) void stats_final_kernel(
    const float* __restrict__ partials, int nblocks,
    const float* __restrict__ pmax, const float* __restrict__ pmin,
    const float* __restrict__ gA, const float* __restrict__ btA,
    float* __restrict__ out) {
  const int o = blockIdx.x;
  const int t = threadIdx.x;
  double s1 = 0.0, s2 = 0.0;
  for (int blk = t; blk < nblocks; blk += 256) {
    s1 += (double)partials[(size_t)blk * 256 + o];
    s2 += (double)partials[(size_t)blk * 256 + 128 + o];
  }
  __shared__ double r1[256], r2[256];
  __shared__ float sMean, sRstd;
  r1[t] = s1; r2[t] = s2;
  __syncthreads();
  for (int st = 128; st > 0; st >>= 1) {
    if (t < st) { r1[t] += r1[t + st]; r2[t] += r2[t + st]; }
    __syncthreads();
  }
  if (t == 0) {
    const double Nr = 262144.0;
    double mean = r1[0] / Nr;
    double var = r2[0] / Nr - mean * mean;
    sMean = (float)mean;
    sRstd = (float)(1.0 / sqrt(var + 1e-5));
  }
  __syncthreads();
  const float mn = sMean, rs = sRstd, gg = gA[o], bb = btA[o];
  const float slope = rs * gg;
  const float* src = (slope >= 0.f) ? pmax : pmin;
  for (int i = t; i < NB * NS; i += 256) {
    int b = i >> 10;
    int s = i & 1023;
    float v = src[(size_t)i * 128 + o];
    float t1 = (v - mn) * rs;
    float t2 = t1 * gg + bb;
    out[(size_t)b * (128 * NS) + o * NS + s] = fmaxf(t2, 0.f);
  }
}

extern "C" void kernel_launch(void* const* d_in, const int* in_sizes, int n_in,
                              void* d_out, int out_size, void* d_ws, size_t ws_size,
                              hipStream_t stream) {
  (void)in_sizes; (void)n_in; (void)out_size; (void)ws_size;
  const float* xyz = (const float*)d_in[0];
  const float* points = (const float*)d_in[1];
  const float* W0 = (const float*)d_in[2];
  const float* b0 = (const float*)d_in[3];
  const float* g0 = (const float*)d_in[4];
  const float* bt0 = (const float*)d_in[5];
  const float* W1 = (const float*)d_in[6];
  const float* b1 = (const float*)d_in[7];
  const float* g1 = (const float*)d_in[8];
  const float* bt1 = (const float*)d_in[9];
  const float* W2 = (const float*)d_in[10];
  const float* b2 = (const float*)d_in[11];
  const float* g2 = (const float*)d_in[12];
  const float* bt2 = (const float*)d_in[13];
  float* out = (float*)d_out;

  float* ws = (float*)d_ws;
  size_t off = 0;
  float* newxyz = ws + off;  off += (size_t)NB * NS * 3;
  int* idx = (int*)(ws + off); off += (size_t)NB * NS * NK;
  float* P1 = ws + off;      off += (size_t)NB * NPTS * 64;
  float* y1 = ws + off;      off += (size_t)NB * NS * 64 * 32;
  float* partials = ws + off; off += (size_t)8192 * 256;
  float* scaleA = ws + off;  off += 128;
  float* shiftA = ws + off;  off += 128;
  float* pmaxb = ws + off;   off += (size_t)NB * NS * 128;
  float* pminb = ws + off;   off += (size_t)NB * NS * 128;

  // blocks 0-7: single-wave fps; blocks 8-519: pgemm hidden on idle CUs
  fps_pgemm_kernel<<<520, 64, 0, stream>>>(xyz, out, newxyz, points, W0, b0, P1);
  query_gstats_kernel<<<2048, 256, 0, stream>>>(xyz, newxyz, P1, W0, idx, partials);
  stats_kernel<64><<<64, 256, 0, stream>>>(partials, 2048, g0, bt0, scaleA, shiftA);
  conv1_kernel<<<4096, 256, 0, stream>>>(xyz, P1, idx, newxyz, W0, W1, b1,
                                         scaleA, shiftA, y1, partials);
  stats_kernel<64><<<64, 256, 0, stream>>>(partials, 4096, g1, bt1, scaleA, shiftA);
  conv_kernel<64, 128, 1, 2><<<8192, 256, 0, stream>>>(
      y1, W2, b2, scaleA, shiftA, nullptr, pmaxb, pminb, partials);
  stats_final_kernel<<<128, 256, 0, stream>>>(partials, 8192, pmaxb, pminb,
                                              g2, bt2, out + NB * NS * 3);
}

// Round 14
// 1008.787 us; speedup vs baseline: 1.7436x; 1.7436x over previous
//
#include <hip/hip_runtime.h>
#include <cstddef>
#include <cstdint>

#define NB 8
#define NPTS 4096
#define NS 1024
#define NK 32
#define ND 64

typedef __attribute__((ext_vector_type(8))) short bf16x8;  // 8 bf16 (4 VGPRs)
typedef __attribute__((ext_vector_type(4))) float f32x4;

__device__ __forceinline__ short f2bf(float f) {  // RNE f32->bf16
  unsigned u = __float_as_uint(f);
  u += 0x7FFF + ((u >> 16) & 1);
  return (short)(u >> 16);
}

// ------------------------------------------------------------------
// fps+pgemm hetero-grid kernel (R12 verbatim — fps floored at ~700us).
// ------------------------------------------------------------------
#define DPP_IMAX(v, ctrl)                                                     \
  {                                                                           \
    int _o = __builtin_amdgcn_update_dpp(v, v, ctrl, 0xf, 0xf, false);        \
    v = (_o > v) ? _o : v;                                                    \
  }

#define DPP_U64MAX(hi, lo, ctrl)                                              \
  {                                                                           \
    unsigned _nh = (unsigned)__builtin_amdgcn_update_dpp((int)(hi), (int)(hi),\
                                                         ctrl, 0xf, 0xf, false);\
    unsigned _nl = (unsigned)__builtin_amdgcn_update_dpp((int)(lo), (int)(lo),\
                                                         ctrl, 0xf, 0xf, false);\
    bool _gt = (_nh > (hi)) || (_nh == (hi) && _nl > (lo));                   \
    hi = _gt ? _nh : (hi);                                                    \
    lo = _gt ? _nl : (lo);                                                    \
  }

// group-of-8 sum via row_shr (lanes 7 mod 8 hold their group's sum)
#define DPP_FADD(v, ctrl)                                                     \
  {                                                                           \
    int _t = __builtin_amdgcn_update_dpp(__float_as_int(v), __float_as_int(v),\
                                         ctrl, 0xf, 0xf, false);              \
    v = v + __int_as_float(_t);                                               \
  }

// 16-lane reductions (only lane 15 mod 16 result is consumed)
#define DPP_RED16(v, OP)                                                      \
  {                                                                           \
    int _i;                                                                   \
    _i = __builtin_amdgcn_update_dpp(__float_as_int(v), __float_as_int(v), 0x111, 0xf, 0xf, false); \
    v = OP(v, __int_as_float(_i));                                            \
    _i = __builtin_amdgcn_update_dpp(__float_as_int(v), __float_as_int(v), 0x112, 0xf, 0xf, false); \
    v = OP(v, __int_as_float(_i));                                            \
    _i = __builtin_amdgcn_update_dpp(__float_as_int(v), __float_as_int(v), 0x114, 0xf, 0xf, false); \
    v = OP(v, __int_as_float(_i));                                            \
    _i = __builtin_amdgcn_update_dpp(__float_as_int(v), __float_as_int(v), 0x118, 0xf, 0xf, false); \
    v = OP(v, __int_as_float(_i));                                            \
  }

__device__ __forceinline__ float fadd_op(float a, float b) { return a + b; }

__global__ __launch_bounds__(512) void fps_pgemm_kernel(
    const float* __restrict__ xyz, float* __restrict__ out_newxyz,
    float* __restrict__ ws_newxyz, const float* __restrict__ points,
    const float* __restrict__ W0, const float* __restrict__ b0g,
    float* __restrict__ P1) {
  __shared__ __align__(16) char smem[53376];
  const int t = threadIdx.x;

  if (blockIdx.x < 8) {
    // ---------------- FPS ----------------
    float* sXYZ = (float*)smem;                                    // 49152 B
    unsigned long long(*sRed)[8] =
        (unsigned long long(*)[8])(smem + 49152);                  // 128 B
    int* sWidx = (int*)(smem + 49280);                             // 4096 B
    const int b = blockIdx.x;
    const int wave = t >> 6;
    const int lane = t & 63;
    const float* xb = xyz + (size_t)b * 3 * NPTS;

    for (int i = t; i < NPTS; i += 512) {
      sXYZ[i * 3 + 0] = xb[i];
      sXYZ[i * 3 + 1] = xb[NPTS + i];
      sXYZ[i * 3 + 2] = xb[2 * NPTS + i];
    }
    if (t == 0) sWidx[0] = 0;

    float px[8], py[8], pz[8], dist[8];
    {
      float4 a0 = ((const float4*)xb)[2 * t];
      float4 a1 = ((const float4*)xb)[2 * t + 1];
      float4 b0v = ((const float4*)(xb + NPTS))[2 * t];
      float4 b1v = ((const float4*)(xb + NPTS))[2 * t + 1];
      float4 c0 = ((const float4*)(xb + 2 * NPTS))[2 * t];
      float4 c1 = ((const float4*)(xb + 2 * NPTS))[2 * t + 1];
      px[0] = a0.x; px[1] = a0.y; px[2] = a0.z; px[3] = a0.w;
      px[4] = a1.x; px[5] = a1.y; px[6] = a1.z; px[7] = a1.w;
      py[0] = b0v.x; py[1] = b0v.y; py[2] = b0v.z; py[3] = b0v.w;
      py[4] = b1v.x; py[5] = b1v.y; py[6] = b1v.z; py[7] = b1v.w;
      pz[0] = c0.x; pz[1] = c0.y; pz[2] = c0.z; pz[3] = c0.w;
      pz[4] = c1.x; pz[5] = c1.y; pz[6] = c1.z; pz[7] = c1.w;
    }
#pragma unroll
    for (int j = 0; j < 8; ++j) dist[j] = 1e10f;

    float cx = xb[0], cy = xb[NPTS], cz = xb[2 * NPTS];  // centroid 0

    for (int s = 0; s < NS; ++s) {
#pragma unroll
      for (int j = 0; j < 8; ++j) {
        float dx = __fadd_rn(px[j], -cx);
        float dy = __fadd_rn(py[j], -cy);
        float dz = __fadd_rn(pz[j], -cz);
        float d = __fadd_rn(__fadd_rn(__fmul_rn(dx, dx), __fmul_rn(dy, dy)),
                            __fmul_rn(dz, dz));
        dist[j] = fminf(dist[j], d);
      }
      float m = fmaxf(fmaxf(fmaxf(dist[0], dist[1]), fmaxf(dist[2], dist[3])),
                      fmaxf(fmaxf(dist[4], dist[5]), fmaxf(dist[6], dist[7])));
      int v = __float_as_int(m);
      DPP_IMAX(v, 0x111)
      DPP_IMAX(v, 0x112)
      DPP_IMAX(v, 0x114)
      DPP_IMAX(v, 0x118)
      DPP_IMAX(v, 0x142)
      DPP_IMAX(v, 0x143)
      const int wm_i = __builtin_amdgcn_readlane(v, 63);
      const float wm = __int_as_float(wm_i);
      unsigned long long claim = __ballot(m == wm);
      int firstlane = __ffsll(claim) - 1;
      if (lane == firstlane) {
        int j = 7;
#pragma unroll
        for (int jj = 6; jj >= 0; --jj)
          if (dist[jj] == wm) j = jj;
        unsigned widx = (unsigned)(t * 8 + j);
        sRed[s & 1][wave] = ((unsigned long long)(unsigned)wm_i << 32) |
                            (unsigned long long)(0xFFFFFFFFu - widx);
      }
      __syncthreads();
      unsigned long long k = sRed[s & 1][lane & 7];
      unsigned h2 = (unsigned)(k >> 32), l2 = (unsigned)k;
      DPP_U64MAX(h2, l2, 0x111)
      DPP_U64MAX(h2, l2, 0x112)
      DPP_U64MAX(h2, l2, 0x114)
      const unsigned gl = (unsigned)__builtin_amdgcn_readlane((int)l2, 7);
      const int widx = (int)(0xFFFFFFFFu - gl);
      cx = sXYZ[widx * 3 + 0];
      cy = sXYZ[widx * 3 + 1];
      cz = sXYZ[widx * 3 + 2];
      if (t == 0 && s < NS - 1) sWidx[s + 1] = widx;
    }
    __syncthreads();
    for (int s2 = t; s2 < NS; s2 += 512) {
      int w = sWidx[s2];
      float x = sXYZ[w * 3 + 0], y = sXYZ[w * 3 + 1], z = sXYZ[w * 3 + 2];
      out_newxyz[b * 3 * NS + s2] = x;
      out_newxyz[b * 3 * NS + NS + s2] = y;
      out_newxyz[b * 3 * NS + 2 * NS + s2] = z;
      ws_newxyz[((b << 10) + s2) * 3 + 0] = x;
      ws_newxyz[((b << 10) + s2) * 3 + 1] = y;
      ws_newxyz[((b << 10) + s2) * 3 + 2] = z;
    }
  } else {
    // ---------------- pgemm: P1[b][n][o] = points·W0[:,3:] + b0 ----------
    float* sP = (float*)smem;            // 16384 B  [c][n]
    float* sW = (float*)(smem + 16384);  // 17408 B  [c][o] pitch 68
    float* sB = (float*)(smem + 33792);  // 256 B
    const int blk = blockIdx.x - 8;      // 0..511
    const int bb = blk >> 6;
    const int n0 = (blk & 63) * 64;
    const float* pb = points + (size_t)bb * ND * NPTS;
    for (int f = t; f < 4096; f += 512) {
      int c = f >> 6, n = f & 63;
      sP[f] = pb[c * NPTS + n0 + n];
    }
    for (int f = t; f < 4096; f += 512) {
      int c = f >> 6, o = f & 63;
      sW[c * 68 + o] = W0[o * 67 + 3 + c];
    }
    if (t < 64) sB[t] = b0g[t];
    __syncthreads();
    if (t < 256) {
      const int nl = (t & 15) * 4;
      const int ol = (t >> 4) * 4;
      float acc[4][4];
#pragma unroll
      for (int i = 0; i < 4; ++i)
#pragma unroll
        for (int j = 0; j < 4; ++j) acc[i][j] = 0.f;
#pragma unroll 4
      for (int c = 0; c < 64; ++c) {
        float4 xv = *(const float4*)(sP + c * 64 + nl);
        float4 wv = *(const float4*)(sW + c * 68 + ol);
        float xa[4] = {xv.x, xv.y, xv.z, xv.w};
        float wa[4] = {wv.x, wv.y, wv.z, wv.w};
#pragma unroll
        for (int i = 0; i < 4; ++i)
#pragma unroll
          for (int j = 0; j < 4; ++j) acc[i][j] += xa[i] * wa[j];
      }
#pragma unroll
      for (int i = 0; i < 4; ++i) {
        float4 v = make_float4(acc[i][0] + sB[ol + 0], acc[i][1] + sB[ol + 1],
                               acc[i][2] + sB[ol + 2], acc[i][3] + sB[ol + 3]);
        *(float4*)(P1 + ((size_t)(bb << 12) + n0 + nl + i) * 64 + ol) = v;
      }
    }
  }
}

// ------------------------------------------------------------------
// Ball query + layer-0 gather stats fused (R12 verbatim)
// ------------------------------------------------------------------
__global__ __launch_bounds__(256) void query_gstats_kernel(
    const float* __restrict__ xyz, const float* __restrict__ ws_newxyz,
    const float* __restrict__ P1, const float* __restrict__ W0,
    int* __restrict__ idx_ws, float* __restrict__ partials) {
  const int w = threadIdx.x >> 6;
  const int lane = threadIdx.x & 63;
  const int p = blockIdx.x * 4 + w;  // 8192 pairs
  const int b = p >> 10;
  __shared__ int sIdx[4][32];
  __shared__ float sWS[4][64];
  __shared__ float sWQ[4][64];
  const float* xb = xyz + (size_t)b * 3 * NPTS;
  const float cx = ws_newxyz[p * 3 + 0];
  const float cy = ws_newxyz[p * 3 + 1];
  const float cz = ws_newxyz[p * 3 + 2];
  const float ss = __fadd_rn(__fadd_rn(__fmul_rn(cx, cx), __fmul_rn(cy, cy)), __fmul_rn(cz, cz));
  const float r2 = (float)(0.4 * 0.4);
  int cnt = 0;
  for (int ci = 0; ci < 64 && cnt < 32; ++ci) {
    int n = ci * 64 + lane;
    float x = xb[n], y = xb[NPTS + n], z = xb[2 * NPTS + n];
    float dot = __fadd_rn(__fadd_rn(__fmul_rn(cx, x), __fmul_rn(cy, y)), __fmul_rn(cz, z));
    float dd = __fadd_rn(__fadd_rn(__fmul_rn(x, x), __fmul_rn(y, y)), __fmul_rn(z, z));
    float d = __fmul_rn(-2.0f, dot);
    d = __fadd_rn(d, ss);
    d = __fadd_rn(d, dd);
    d = fmaxf(d, 1e-12f);  // clip
    bool inc = (d <= r2);
    unsigned long long m = __ballot(inc);
    int slot = cnt + (int)__popcll(m & ((1ull << lane) - 1ull));
    if (inc && slot < 32) sIdx[w][slot] = n;
    cnt += (int)__popcll(m);
  }
  if (lane < 32) {
    int v;
    if (lane < cnt) v = sIdx[w][lane];
    else v = (cnt > 0) ? sIdx[w][0] : 0;
    idx_ws[p * 32 + lane] = v;
    sIdx[w][lane] = v;
  }
  const float wx = W0[lane * 67 + 0];
  const float wy = W0[lane * 67 + 1];
  const float wz = W0[lane * 67 + 2];
  float ssum = 0.f, ssq = 0.f;
  for (int r = 0; r < 32; ++r) {
    const int n = sIdx[w][r];
    float P1v = P1[((size_t)(b << 12) + n) * 64 + lane];
    float dx = __fadd_rn(xb[n], -cx);
    float dy = __fadd_rn(xb[NPTS + n], -cy);
    float dz = __fadd_rn(xb[2 * NPTS + n], -cz);
    float y = P1v + (dx * wx + dy * wy + dz * wz);
    ssum += y;
    ssq += y * y;
  }
  sWS[w][lane] = ssum;
  sWQ[w][lane] = ssq;
  __syncthreads();
  const int t = threadIdx.x;
  if (t < 64) {
    float s1 = sWS[0][t] + sWS[1][t] + sWS[2][t] + sWS[3][t];
    float s2 = sWQ[0][t] + sWQ[1][t] + sWQ[2][t] + sWQ[3][t];
    partials[(size_t)blockIdx.x * 128 + t] = s1;
    partials[(size_t)blockIdx.x * 128 + 64 + t] = s2;
  }
}

// ------------------------------------------------------------------
// conv1 with gather-recompute staging (R12 verbatim)
// ------------------------------------------------------------------
__global__ __launch_bounds__(256) void conv1_kernel(
    const float* __restrict__ xyz, const float* __restrict__ P1,
    const int* __restrict__ idx_ws, const float* __restrict__ cen_ws,
    const float* __restrict__ W0, const float* __restrict__ W1,
    const float* __restrict__ bias, const float* __restrict__ scaleA,
    const float* __restrict__ shiftA, float* __restrict__ y1,
    float* __restrict__ partials) {
  constexpr int CIN = 64, COUT = 64, WP = 68, TPS = 128;
  __shared__ __align__(16) float sW[CIN * WP];
  __shared__ __align__(16) float sX[2 * CIN * 32];
  __shared__ float sY[64 * 65];
  __shared__ int sIdx[64];
  __shared__ float sCen[2 * 4];
  __shared__ float sScale[CIN];
  __shared__ float sShift[CIN];
  __shared__ float sSum[COUT];
  __shared__ float sSq[COUT];

  const int t = threadIdx.x;
  const int wave = t >> 6, lane = t & 63;
  const int pair0 = blockIdx.x * 2;
  const int b = pair0 >> 10;

  for (int f = t; f < CIN * COUT; f += 256) {
    int o = f / CIN;
    int c = f - o * CIN;
    sW[c * WP + o] = W1[f];
  }
  if (t < CIN) { sScale[t] = scaleA[t]; sShift[t] = shiftA[t]; }
  if (t < COUT) { sSum[t] = 0.f; sSq[t] = 0.f; }
  if (t < 64) sIdx[t] = idx_ws[pair0 * 32 + t];
  if (t < 6) sCen[(t / 3) * 4 + (t % 3)] = cen_ws[pair0 * 3 + t];
  const float wx = W0[lane * 67 + 0];
  const float wy = W0[lane * 67 + 1];
  const float wz = W0[lane * 67 + 2];
  __syncthreads();
  const float* xb = xyz + (size_t)b * 3 * NPTS;
  for (int r = wave; r < 64; r += 4) {
    const int sl = r >> 5;
    const int n = sIdx[r];
    float P1v = P1[((size_t)(b << 12) + n) * 64 + lane];
    float dx = __fadd_rn(xb[n], -sCen[sl * 4 + 0]);
    float dy = __fadd_rn(xb[NPTS + n], -sCen[sl * 4 + 1]);
    float dz = __fadd_rn(xb[2 * NPTS + n], -sCen[sl * 4 + 2]);
    sY[r * 65 + lane] = P1v + (dx * wx + dy * wy + dz * wz);
  }
  __syncthreads();
  for (int f = t; f < 2 * CIN * 32; f += 256) {
    int sl = f >> 11;
    int rmd = f & 2047;
    int o = rmd >> 5, k = rmd & 31;
    float v = sY[(sl * 32 + k) * 65 + o];
    v = v * sScale[o] + sShift[o];
    sX[f] = fmaxf(v, 0.f);
  }
  __syncthreads();

  const int sl = t / TPS;
  const int tl = t - sl * TPS;
  const int k0 = (tl & 7) * 4;
  const int o0 = (tl >> 3) * 4;

  float acc[4][4];
#pragma unroll
  for (int i = 0; i < 4; ++i)
#pragma unroll
    for (int j = 0; j < 4; ++j) acc[i][j] = 0.f;

  const float* xrow = sX + sl * (CIN * 32);
#pragma unroll 4
  for (int c = 0; c < CIN; ++c) {
    float4 xv = *(const float4*)(xrow + c * 32 + k0);
    float4 wv = *(const float4*)(sW + c * WP + o0);
    float xa[4] = {xv.x, xv.y, xv.z, xv.w};
    float wa[4] = {wv.x, wv.y, wv.z, wv.w};
#pragma unroll
    for (int i = 0; i < 4; ++i)
#pragma unroll
      for (int j = 0; j < 4; ++j) acc[i][j] += wa[i] * xa[j];
  }
#pragma unroll
  for (int i = 0; i < 4; ++i) {
    float bo = bias[o0 + i];
#pragma unroll
    for (int j = 0; j < 4; ++j) acc[i][j] += bo;
  }
#pragma unroll
  for (int i = 0; i < 4; ++i) {
    float s1 = (acc[i][0] + acc[i][1]) + (acc[i][2] + acc[i][3]);
    float s2 = (acc[i][0] * acc[i][0] + acc[i][1] * acc[i][1]) +
               (acc[i][2] * acc[i][2] + acc[i][3] * acc[i][3]);
    DPP_FADD(s1, 0x111)
    DPP_FADD(s1, 0x112)
    DPP_FADD(s1, 0x114)
    DPP_FADD(s2, 0x111)
    DPP_FADD(s2, 0x112)
    DPP_FADD(s2, 0x114)
    if ((t & 7) == 7) {
      atomicAdd(&sSum[o0 + i], s1);
      atomicAdd(&sSq[o0 + i], s2);
    }
  }
#pragma unroll
  for (int i = 0; i < 4; ++i) {
    float4 v = make_float4(acc[i][0], acc[i][1], acc[i][2], acc[i][3]);
    *(float4*)(y1 + (size_t)(pair0 + sl) * COUT * 32 + (o0 + i) * 32 + k0) = v;
  }
  __syncthreads();
  if (t < COUT) {
    partials[(size_t)blockIdx.x * (COUT * 2) + t] = sSum[t];
    partials[(size_t)blockIdx.x * (COUT * 2) + COUT + t] = sSq[t];
  }
}

// ------------------------------------------------------------------
// conv2 via MFMA bf16: one s per block. C = W2(128x64) x X(64x32).
// 16x16x32 bf16 mfma; A[m=lane&15][k=quad*8+j] from bf16 W2 tile,
// B[k=quad*8+j][n=lane&15] from bf16 X tile (pitch 72 -> aligned b128,
// 2-way banked = free). Epilogue: bias + sum/sumsq + max/min pool via
// 16-lane DPP reductions (lane15-of-16 holds result; C-layout
// col=lane&15, row=quad*4+reg). fp32 accumulate; stats stay fp32/f64.
// ------------------------------------------------------------------
__global__ __launch_bounds__(256) void conv2_mfma_kernel(
    const float* __restrict__ y1, const float* __restrict__ W2,
    const float* __restrict__ b2, const float* __restrict__ scaleA,
    const float* __restrict__ shiftA, float* __restrict__ pmax,
    float* __restrict__ pmin, float* __restrict__ partials) {
  __shared__ __align__(16) short sW2[128 * 72];  // 18432 B, [o][c] pitch 72
  __shared__ __align__(16) short sXb[32 * 72];   // 4608 B,  [n][c] pitch 72
  __shared__ float sScale[64], sShift[64], sBias[128];
  __shared__ float sSum[128], sSq[128], sMax[128], sMin[128];

  const int t = threadIdx.x;
  const int s = blockIdx.x;
  const int lane = t & 63;
  const int wv = t >> 6;
  const int quad = lane >> 4;
  const int l15 = lane & 15;

  if (t < 64) { sScale[t] = scaleA[t]; sShift[t] = shiftA[t]; }
  if (t < 128) sBias[t] = b2[t];
  for (int f = t; f < 8192; f += 256) {
    int o = f >> 6, c = f & 63;
    sW2[o * 72 + c] = f2bf(W2[f]);
  }
  for (int f = t; f < 2048; f += 256) {
    int o = f >> 5, k = f & 31;
    float v = y1[(size_t)s * 2048 + f];
    v = v * sScale[o] + sShift[o];
    v = fmaxf(v, 0.f);
    sXb[k * 72 + o] = f2bf(v);
  }
  __syncthreads();

  f32x4 a00 = {0.f, 0.f, 0.f, 0.f}, a01 = {0.f, 0.f, 0.f, 0.f};
  f32x4 a10 = {0.f, 0.f, 0.f, 0.f}, a11 = {0.f, 0.f, 0.f, 0.f};
#pragma unroll
  for (int kh = 0; kh < 2; ++kh) {
    const int kc = kh * 32 + quad * 8;
    bf16x8 A0 = *(const bf16x8*)(sW2 + (wv * 32 + l15) * 72 + kc);
    bf16x8 A1 = *(const bf16x8*)(sW2 + (wv * 32 + 16 + l15) * 72 + kc);
    bf16x8 B0 = *(const bf16x8*)(sXb + l15 * 72 + kc);
    bf16x8 B1 = *(const bf16x8*)(sXb + (16 + l15) * 72 + kc);
    a00 = __builtin_amdgcn_mfma_f32_16x16x32_bf16(A0, B0, a00, 0, 0, 0);
    a01 = __builtin_amdgcn_mfma_f32_16x16x32_bf16(A0, B1, a01, 0, 0, 0);
    a10 = __builtin_amdgcn_mfma_f32_16x16x32_bf16(A1, B0, a10, 0, 0, 0);
    a11 = __builtin_amdgcn_mfma_f32_16x16x32_bf16(A1, B1, a11, 0, 0, 0);
  }

#pragma unroll
  for (int mi = 0; mi < 2; ++mi) {
    f32x4 L = mi ? a10 : a00;
    f32x4 R = mi ? a11 : a01;
    const int m0 = wv * 32 + mi * 16;
#pragma unroll
    for (int reg = 0; reg < 4; ++reg) {
      const int m = m0 + quad * 4 + reg;
      const float bb = sBias[m];
      float v0 = L[reg] + bb;
      float v1 = R[reg] + bb;
      float s1 = v0 + v1;
      float s2 = v0 * v0 + v1 * v1;
      float mx = fmaxf(v0, v1);
      float mn = fminf(v0, v1);
      DPP_RED16(s1, fadd_op)
      DPP_RED16(s2, fadd_op)
      DPP_RED16(mx, fmaxf)
      DPP_RED16(mn, fminf)
      if (l15 == 15) {
        sSum[m] = s1;
        sSq[m] = s2;
        sMax[m] = mx;
        sMin[m] = mn;
      }
    }
  }
  __syncthreads();
  if (t < 128) {
    partials[(size_t)s * 256 + t] = sSum[t];
    partials[(size_t)s * 256 + 128 + t] = sSq[t];
    pmax[(size_t)s * 128 + t] = sMax[t];
    pmin[(size_t)s * 128 + t] = sMin[t];
  }
}

// one block per channel: f64 reduce -> fused scale/shift for next layer
template <int COUT>
__global__ __launch_bounds__(256) void stats_kernel(const float* __restrict__ partials,
                                                    int nblocks,
                                                    const float* __restrict__ gA,
                                                    const float* __restrict__ btA,
                                                    float* __restrict__ scaleA,
                                                    float* __restrict__ shiftA) {
  const int o = blockIdx.x;
  const int t = threadIdx.x;
  double s1 = 0.0, s2 = 0.0;
  for (int blk = t; blk < nblocks; blk += 256) {
    s1 += (double)partials[(size_t)blk * (COUT * 2) + o];
    s2 += (double)partials[(size_t)blk * (COUT * 2) + COUT + o];
  }
  __shared__ double r1[256], r2[256];
  r1[t] = s1; r2[t] = s2;
  __syncthreads();
  for (int st = 128; st > 0; st >>= 1) {
    if (t < st) { r1[t] += r1[t + st]; r2[t] += r2[t + st]; }
    __syncthreads();
  }
  if (t == 0) {
    const double Nr = 262144.0;  // B*K*S
    double mean = r1[0] / Nr;
    double var = r2[0] / Nr - mean * mean;
    double rstd = 1.0 / sqrt(var + 1e-5);
    double sc = rstd * (double)gA[o];
    scaleA[o] = (float)sc;
    shiftA[o] = (float)((double)btA[o] - mean * sc);
  }
}

// layer-2 stats + final normalize fused: one block per channel (128).
__global__ __launch_bounds__(256) void stats_final_kernel(
    const float* __restrict__ partials, int nblocks,
    const float* __restrict__ pmax, const float* __restrict__ pmin,
    const float* __restrict__ gA, const float* __restrict__ btA,
    float* __restrict__ out) {
  const int o = blockIdx.x;
  const int t = threadIdx.x;
  double s1 = 0.0, s2 = 0.0;
  for (int blk = t; blk < nblocks; blk += 256) {
    s1 += (double)partials[(size_t)blk * 256 + o];
    s2 += (double)partials[(size_t)blk * 256 + 128 + o];
  }
  __shared__ double r1[256], r2[256];
  __shared__ float sMean, sRstd;
  r1[t] = s1; r2[t] = s2;
  __syncthreads();
  for (int st = 128; st > 0; st >>= 1) {
    if (t < st) { r1[t] += r1[t + st]; r2[t] += r2[t + st]; }
    __syncthreads();
  }
  if (t == 0) {
    const double Nr = 262144.0;
    double mean = r1[0] / Nr;
    double var = r2[0] / Nr - mean * mean;
    sMean = (float)mean;
    sRstd = (float)(1.0 / sqrt(var + 1e-5));
  }
  __syncthreads();
  const float mn = sMean, rs = sRstd, gg = gA[o], bb = btA[o];
  const float slope = rs * gg;
  const float* src = (slope >= 0.f) ? pmax : pmin;
  for (int i = t; i < NB * NS; i += 256) {
    int b = i >> 10;
    int s = i & 1023;
    float v = src[(size_t)i * 128 + o];
    float t1 = (v - mn) * rs;
    float t2 = t1 * gg + bb;
    out[(size_t)b * (128 * NS) + o * NS + s] = fmaxf(t2, 0.f);
  }
}

extern "C" void kernel_launch(void* const* d_in, const int* in_sizes, int n_in,
                              void* d_out, int out_size, void* d_ws, size_t ws_size,
                              hipStream_t stream) {
  (void)in_sizes; (void)n_in; (void)out_size; (void)ws_size;
  const float* xyz = (const float*)d_in[0];
  const float* points = (const float*)d_in[1];
  const float* W0 = (const float*)d_in[2];
  const float* b0 = (const float*)d_in[3];
  const float* g0 = (const float*)d_in[4];
  const float* bt0 = (const float*)d_in[5];
  const float* W1 = (const float*)d_in[6];
  const float* b1 = (const float*)d_in[7];
  const float* g1 = (const float*)d_in[8];
  const float* bt1 = (const float*)d_in[9];
  const float* W2 = (const float*)d_in[10];
  const float* b2 = (const float*)d_in[11];
  const float* g2 = (const float*)d_in[12];
  const float* bt2 = (const float*)d_in[13];
  float* out = (float*)d_out;

  float* ws = (float*)d_ws;
  size_t off = 0;
  float* newxyz = ws + off;  off += (size_t)NB * NS * 3;
  int* idx = (int*)(ws + off); off += (size_t)NB * NS * NK;
  float* P1 = ws + off;      off += (size_t)NB * NPTS * 64;
  float* y1 = ws + off;      off += (size_t)NB * NS * 64 * 32;
  float* partials = ws + off; off += (size_t)8192 * 256;
  float* scaleA = ws + off;  off += 128;
  float* shiftA = ws + off;  off += 128;
  float* pmaxb = ws + off;   off += (size_t)NB * NS * 128;
  float* pminb = ws + off;   off += (size_t)NB * NS * 128;

  // blocks 0-7: fps (8 CUs); blocks 8-519: pgemm hidden on idle CUs
  fps_pgemm_kernel<<<520, 512, 0, stream>>>(xyz, out, newxyz, points, W0, b0, P1);
  query_gstats_kernel<<<2048, 256, 0, stream>>>(xyz, newxyz, P1, W0, idx, partials);
  stats_kernel<64><<<64, 256, 0, stream>>>(partials, 2048, g0, bt0, scaleA, shiftA);
  conv1_kernel<<<4096, 256, 0, stream>>>(xyz, P1, idx, newxyz, W0, W1, b1,
                                         scaleA, shiftA, y1, partials);
  stats_kernel<64><<<64, 256, 0, stream>>>(partials, 4096, g1, bt1, scaleA, shiftA);
  conv2_mfma_kernel<<<8192, 256, 0, stream>>>(y1, W2, b2, scaleA, shiftA,
                                              pmaxb, pminb, partials);
  stats_final_kernel<<<128, 256, 0, stream>>>(partials, 8192, pmaxb, pminb,
                                              g2, bt2, out + NB * NS * 3);
}

// Round 15
// 969.177 us; speedup vs baseline: 1.8148x; 1.0409x over previous
//
#include <hip/hip_runtime.h>
#include <cstddef>
#include <cstdint>

#define NB 8
#define NPTS 4096
#define NS 1024
#define NK 32
#define ND 64

typedef __attribute__((ext_vector_type(8))) short bf16x8;  // 8 bf16 (4 VGPRs)
typedef __attribute__((ext_vector_type(4))) float f32x4;

__device__ __forceinline__ short f2bf(float f) {  // RNE f32->bf16
  unsigned u = __float_as_uint(f);
  u += 0x7FFF + ((u >> 16) & 1);
  return (short)(u >> 16);
}

// ------------------------------------------------------------------
// fps+pgemm hetero-grid kernel (R12 verbatim — fps floored at ~700us).
// ------------------------------------------------------------------
#define DPP_IMAX(v, ctrl)                                                     \
  {                                                                           \
    int _o = __builtin_amdgcn_update_dpp(v, v, ctrl, 0xf, 0xf, false);        \
    v = (_o > v) ? _o : v;                                                    \
  }

#define DPP_U64MAX(hi, lo, ctrl)                                              \
  {                                                                           \
    unsigned _nh = (unsigned)__builtin_amdgcn_update_dpp((int)(hi), (int)(hi),\
                                                         ctrl, 0xf, 0xf, false);\
    unsigned _nl = (unsigned)__builtin_amdgcn_update_dpp((int)(lo), (int)(lo),\
                                                         ctrl, 0xf, 0xf, false);\
    bool _gt = (_nh > (hi)) || (_nh == (hi) && _nl > (lo));                   \
    hi = _gt ? _nh : (hi);                                                    \
    lo = _gt ? _nl : (lo);                                                    \
  }

// group-of-8 sum via row_shr (lanes 7 mod 8 hold their group's sum)
#define DPP_FADD(v, ctrl)                                                     \
  {                                                                           \
    int _t = __builtin_amdgcn_update_dpp(__float_as_int(v), __float_as_int(v),\
                                         ctrl, 0xf, 0xf, false);              \
    v = v + __int_as_float(_t);                                               \
  }

// 16-lane reductions (only lane 15 mod 16 result is consumed)
#define DPP_RED16(v, OP)                                                      \
  {                                                                           \
    int _i;                                                                   \
    _i = __builtin_amdgcn_update_dpp(__float_as_int(v), __float_as_int(v), 0x111, 0xf, 0xf, false); \
    v = OP(v, __int_as_float(_i));                                            \
    _i = __builtin_amdgcn_update_dpp(__float_as_int(v), __float_as_int(v), 0x112, 0xf, 0xf, false); \
    v = OP(v, __int_as_float(_i));                                            \
    _i = __builtin_amdgcn_update_dpp(__float_as_int(v), __float_as_int(v), 0x114, 0xf, 0xf, false); \
    v = OP(v, __int_as_float(_i));                                            \
    _i = __builtin_amdgcn_update_dpp(__float_as_int(v), __float_as_int(v), 0x118, 0xf, 0xf, false); \
    v = OP(v, __int_as_float(_i));                                            \
  }

__device__ __forceinline__ float fadd_op(float a, float b) { return a + b; }

__global__ __launch_bounds__(512) void fps_pgemm_kernel(
    const float* __restrict__ xyz, float* __restrict__ out_newxyz,
    float* __restrict__ ws_newxyz, const float* __restrict__ points,
    const float* __restrict__ W0, const float* __restrict__ b0g,
    float* __restrict__ P1) {
  __shared__ __align__(16) char smem[53376];
  const int t = threadIdx.x;

  if (blockIdx.x < 8) {
    // ---------------- FPS ----------------
    float* sXYZ = (float*)smem;                                    // 49152 B
    unsigned long long(*sRed)[8] =
        (unsigned long long(*)[8])(smem + 49152);                  // 128 B
    int* sWidx = (int*)(smem + 49280);                             // 4096 B
    const int b = blockIdx.x;
    const int wave = t >> 6;
    const int lane = t & 63;
    const float* xb = xyz + (size_t)b * 3 * NPTS;

    for (int i = t; i < NPTS; i += 512) {
      sXYZ[i * 3 + 0] = xb[i];
      sXYZ[i * 3 + 1] = xb[NPTS + i];
      sXYZ[i * 3 + 2] = xb[2 * NPTS + i];
    }
    if (t == 0) sWidx[0] = 0;

    float px[8], py[8], pz[8], dist[8];
    {
      float4 a0 = ((const float4*)xb)[2 * t];
      float4 a1 = ((const float4*)xb)[2 * t + 1];
      float4 b0v = ((const float4*)(xb + NPTS))[2 * t];
      float4 b1v = ((const float4*)(xb + NPTS))[2 * t + 1];
      float4 c0 = ((const float4*)(xb + 2 * NPTS))[2 * t];
      float4 c1 = ((const float4*)(xb + 2 * NPTS))[2 * t + 1];
      px[0] = a0.x; px[1] = a0.y; px[2] = a0.z; px[3] = a0.w;
      px[4] = a1.x; px[5] = a1.y; px[6] = a1.z; px[7] = a1.w;
      py[0] = b0v.x; py[1] = b0v.y; py[2] = b0v.z; py[3] = b0v.w;
      py[4] = b1v.x; py[5] = b1v.y; py[6] = b1v.z; py[7] = b1v.w;
      pz[0] = c0.x; pz[1] = c0.y; pz[2] = c0.z; pz[3] = c0.w;
      pz[4] = c1.x; pz[5] = c1.y; pz[6] = c1.z; pz[7] = c1.w;
    }
#pragma unroll
    for (int j = 0; j < 8; ++j) dist[j] = 1e10f;

    float cx = xb[0], cy = xb[NPTS], cz = xb[2 * NPTS];  // centroid 0

    for (int s = 0; s < NS; ++s) {
#pragma unroll
      for (int j = 0; j < 8; ++j) {
        float dx = __fadd_rn(px[j], -cx);
        float dy = __fadd_rn(py[j], -cy);
        float dz = __fadd_rn(pz[j], -cz);
        float d = __fadd_rn(__fadd_rn(__fmul_rn(dx, dx), __fmul_rn(dy, dy)),
                            __fmul_rn(dz, dz));
        dist[j] = fminf(dist[j], d);
      }
      float m = fmaxf(fmaxf(fmaxf(dist[0], dist[1]), fmaxf(dist[2], dist[3])),
                      fmaxf(fmaxf(dist[4], dist[5]), fmaxf(dist[6], dist[7])));
      int v = __float_as_int(m);
      DPP_IMAX(v, 0x111)
      DPP_IMAX(v, 0x112)
      DPP_IMAX(v, 0x114)
      DPP_IMAX(v, 0x118)
      DPP_IMAX(v, 0x142)
      DPP_IMAX(v, 0x143)
      const int wm_i = __builtin_amdgcn_readlane(v, 63);
      const float wm = __int_as_float(wm_i);
      unsigned long long claim = __ballot(m == wm);
      int firstlane = __ffsll(claim) - 1;
      if (lane == firstlane) {
        int j = 7;
#pragma unroll
        for (int jj = 6; jj >= 0; --jj)
          if (dist[jj] == wm) j = jj;
        unsigned widx = (unsigned)(t * 8 + j);
        sRed[s & 1][wave] = ((unsigned long long)(unsigned)wm_i << 32) |
                            (unsigned long long)(0xFFFFFFFFu - widx);
      }
      __syncthreads();
      unsigned long long k = sRed[s & 1][lane & 7];
      unsigned h2 = (unsigned)(k >> 32), l2 = (unsigned)k;
      DPP_U64MAX(h2, l2, 0x111)
      DPP_U64MAX(h2, l2, 0x112)
      DPP_U64MAX(h2, l2, 0x114)
      const unsigned gl = (unsigned)__builtin_amdgcn_readlane((int)l2, 7);
      const int widx = (int)(0xFFFFFFFFu - gl);
      cx = sXYZ[widx * 3 + 0];
      cy = sXYZ[widx * 3 + 1];
      cz = sXYZ[widx * 3 + 2];
      if (t == 0 && s < NS - 1) sWidx[s + 1] = widx;
    }
    __syncthreads();
    for (int s2 = t; s2 < NS; s2 += 512) {
      int w = sWidx[s2];
      float x = sXYZ[w * 3 + 0], y = sXYZ[w * 3 + 1], z = sXYZ[w * 3 + 2];
      out_newxyz[b * 3 * NS + s2] = x;
      out_newxyz[b * 3 * NS + NS + s2] = y;
      out_newxyz[b * 3 * NS + 2 * NS + s2] = z;
      ws_newxyz[((b << 10) + s2) * 3 + 0] = x;
      ws_newxyz[((b << 10) + s2) * 3 + 1] = y;
      ws_newxyz[((b << 10) + s2) * 3 + 2] = z;
    }
  } else {
    // ---------------- pgemm: P1[b][n][o] = points·W0[:,3:] + b0 ----------
    float* sP = (float*)smem;            // 16384 B  [c][n]
    float* sW = (float*)(smem + 16384);  // 17408 B  [c][o] pitch 68
    float* sB = (float*)(smem + 33792);  // 256 B
    const int blk = blockIdx.x - 8;      // 0..511
    const int bb = blk >> 6;
    const int n0 = (blk & 63) * 64;
    const float* pb = points + (size_t)bb * ND * NPTS;
    for (int f = t; f < 4096; f += 512) {
      int c = f >> 6, n = f & 63;
      sP[f] = pb[c * NPTS + n0 + n];
    }
    for (int f = t; f < 4096; f += 512) {
      int c = f >> 6, o = f & 63;
      sW[c * 68 + o] = W0[o * 67 + 3 + c];
    }
    if (t < 64) sB[t] = b0g[t];
    __syncthreads();
    if (t < 256) {
      const int nl = (t & 15) * 4;
      const int ol = (t >> 4) * 4;
      float acc[4][4];
#pragma unroll
      for (int i = 0; i < 4; ++i)
#pragma unroll
        for (int j = 0; j < 4; ++j) acc[i][j] = 0.f;
#pragma unroll 4
      for (int c = 0; c < 64; ++c) {
        float4 xv = *(const float4*)(sP + c * 64 + nl);
        float4 wv = *(const float4*)(sW + c * 68 + ol);
        float xa[4] = {xv.x, xv.y, xv.z, xv.w};
        float wa[4] = {wv.x, wv.y, wv.z, wv.w};
#pragma unroll
        for (int i = 0; i < 4; ++i)
#pragma unroll
          for (int j = 0; j < 4; ++j) acc[i][j] += xa[i] * wa[j];
      }
#pragma unroll
      for (int i = 0; i < 4; ++i) {
        float4 v = make_float4(acc[i][0] + sB[ol + 0], acc[i][1] + sB[ol + 1],
                               acc[i][2] + sB[ol + 2], acc[i][3] + sB[ol + 3]);
        *(float4*)(P1 + ((size_t)(bb << 12) + n0 + nl + i) * 64 + ol) = v;
      }
    }
  }
}

// ------------------------------------------------------------------
// Ball query + layer-0 gather stats fused (R12 verbatim)
// ------------------------------------------------------------------
__global__ __launch_bounds__(256) void query_gstats_kernel(
    const float* __restrict__ xyz, const float* __restrict__ ws_newxyz,
    const float* __restrict__ P1, const float* __restrict__ W0,
    int* __restrict__ idx_ws, float* __restrict__ partials) {
  const int w = threadIdx.x >> 6;
  const int lane = threadIdx.x & 63;
  const int p = blockIdx.x * 4 + w;  // 8192 pairs
  const int b = p >> 10;
  __shared__ int sIdx[4][32];
  __shared__ float sWS[4][64];
  __shared__ float sWQ[4][64];
  const float* xb = xyz + (size_t)b * 3 * NPTS;
  const float cx = ws_newxyz[p * 3 + 0];
  const float cy = ws_newxyz[p * 3 + 1];
  const float cz = ws_newxyz[p * 3 + 2];
  const float ss = __fadd_rn(__fadd_rn(__fmul_rn(cx, cx), __fmul_rn(cy, cy)), __fmul_rn(cz, cz));
  const float r2 = (float)(0.4 * 0.4);
  int cnt = 0;
  for (int ci = 0; ci < 64 && cnt < 32; ++ci) {
    int n = ci * 64 + lane;
    float x = xb[n], y = xb[NPTS + n], z = xb[2 * NPTS + n];
    float dot = __fadd_rn(__fadd_rn(__fmul_rn(cx, x), __fmul_rn(cy, y)), __fmul_rn(cz, z));
    float dd = __fadd_rn(__fadd_rn(__fmul_rn(x, x), __fmul_rn(y, y)), __fmul_rn(z, z));
    float d = __fmul_rn(-2.0f, dot);
    d = __fadd_rn(d, ss);
    d = __fadd_rn(d, dd);
    d = fmaxf(d, 1e-12f);  // clip
    bool inc = (d <= r2);
    unsigned long long m = __ballot(inc);
    int slot = cnt + (int)__popcll(m & ((1ull << lane) - 1ull));
    if (inc && slot < 32) sIdx[w][slot] = n;
    cnt += (int)__popcll(m);
  }
  if (lane < 32) {
    int v;
    if (lane < cnt) v = sIdx[w][lane];
    else v = (cnt > 0) ? sIdx[w][0] : 0;
    idx_ws[p * 32 + lane] = v;
    sIdx[w][lane] = v;
  }
  const float wx = W0[lane * 67 + 0];
  const float wy = W0[lane * 67 + 1];
  const float wz = W0[lane * 67 + 2];
  float ssum = 0.f, ssq = 0.f;
  for (int r = 0; r < 32; ++r) {
    const int n = sIdx[w][r];
    float P1v = P1[((size_t)(b << 12) + n) * 64 + lane];
    float dx = __fadd_rn(xb[n], -cx);
    float dy = __fadd_rn(xb[NPTS + n], -cy);
    float dz = __fadd_rn(xb[2 * NPTS + n], -cz);
    float y = P1v + (dx * wx + dy * wy + dz * wz);
    ssum += y;
    ssq += y * y;
  }
  sWS[w][lane] = ssum;
  sWQ[w][lane] = ssq;
  __syncthreads();
  const int t = threadIdx.x;
  if (t < 64) {
    float s1 = sWS[0][t] + sWS[1][t] + sWS[2][t] + sWS[3][t];
    float s2 = sWQ[0][t] + sWQ[1][t] + sWQ[2][t] + sWQ[3][t];
    partials[(size_t)blockIdx.x * 128 + t] = s1;
    partials[(size_t)blockIdx.x * 128 + 64 + t] = s2;
  }
}

// ------------------------------------------------------------------
// conv1 via MFMA bf16 with fused gather-recompute staging.
// Block = 2 s. Staging writes B-operand layout directly:
// sXb[r=(sl*32+k)][c] bf16 pitch 72 (no fp32 bounce, no transpose).
// A = W1 bf16 [o][c] pitch 72. Wave wv: A rows wv*16..+15; 4 B tiles
// (2 s x 2 16-col halves); 8 mfma. Epilogue: +bias, y1 fp32 write,
// layer-1 sum/sumsq via 16-lane DPP (C: col=lane&15, row=quad*4+reg).
// ------------------------------------------------------------------
__global__ __launch_bounds__(256) void conv1_mfma_kernel(
    const float* __restrict__ xyz, const float* __restrict__ P1,
    const int* __restrict__ idx_ws, const float* __restrict__ cen_ws,
    const float* __restrict__ W0, const float* __restrict__ W1,
    const float* __restrict__ b1, const float* __restrict__ scaleA,
    const float* __restrict__ shiftA, float* __restrict__ y1,
    float* __restrict__ partials) {
  __shared__ __align__(16) short sW1b[64 * 72];  // 9216 B
  __shared__ __align__(16) short sXb[64 * 72];   // 9216 B
  __shared__ int sIdx[64];
  __shared__ float sCen[2 * 4];
  __shared__ float sBias[64], sSum[64], sSq[64];

  const int t = threadIdx.x;
  const int wv = t >> 6, lane = t & 63;
  const int quad = lane >> 4, l15 = lane & 15;
  const int pair0 = blockIdx.x * 2;
  const int b = pair0 >> 10;

  for (int f = t; f < 4096; f += 256) sW1b[(f >> 6) * 72 + (f & 63)] = f2bf(W1[f]);
  if (t < 64) { sBias[t] = b1[t]; sIdx[t] = idx_ws[pair0 * 32 + t]; }
  if (t < 6) sCen[(t / 3) * 4 + (t % 3)] = cen_ws[pair0 * 3 + t];
  const float wx = W0[lane * 67 + 0];
  const float wy = W0[lane * 67 + 1];
  const float wz = W0[lane * 67 + 2];
  const float sc = scaleA[lane];
  const float sh = shiftA[lane];
  __syncthreads();
  const float* xb = xyz + (size_t)b * 3 * NPTS;
  for (int r = wv; r < 64; r += 4) {
    const int sl = r >> 5;
    const int n = sIdx[r];
    float P1v = P1[((size_t)(b << 12) + n) * 64 + lane];
    float dx = __fadd_rn(xb[n], -sCen[sl * 4 + 0]);
    float dy = __fadd_rn(xb[NPTS + n], -sCen[sl * 4 + 1]);
    float dz = __fadd_rn(xb[2 * NPTS + n], -sCen[sl * 4 + 2]);
    float y0 = P1v + (dx * wx + dy * wy + dz * wz);
    sXb[r * 72 + lane] = f2bf(fmaxf(y0 * sc + sh, 0.f));
  }
  __syncthreads();

  f32x4 acc[4];
#pragma unroll
  for (int i = 0; i < 4; ++i) acc[i] = (f32x4){0.f, 0.f, 0.f, 0.f};
#pragma unroll
  for (int kh = 0; kh < 2; ++kh) {
    const int kc = kh * 32 + quad * 8;
    bf16x8 A = *(const bf16x8*)(sW1b + (wv * 16 + l15) * 72 + kc);
#pragma unroll
    for (int ti = 0; ti < 4; ++ti) {
      bf16x8 B = *(const bf16x8*)(sXb + (ti * 16 + l15) * 72 + kc);
      acc[ti] = __builtin_amdgcn_mfma_f32_16x16x32_bf16(A, B, acc[ti], 0, 0, 0);
    }
  }

#pragma unroll
  for (int reg = 0; reg < 4; ++reg) {
    const int m = wv * 16 + quad * 4 + reg;
    const float bb = sBias[m];
    float v[4];
#pragma unroll
    for (int ti = 0; ti < 4; ++ti) {
      v[ti] = acc[ti][reg] + bb;
      y1[(size_t)(pair0 + (ti >> 1)) * 2048 + m * 32 + (ti & 1) * 16 + l15] = v[ti];
    }
    float s1 = (v[0] + v[1]) + (v[2] + v[3]);
    float s2 = (v[0] * v[0] + v[1] * v[1]) + (v[2] * v[2] + v[3] * v[3]);
    DPP_RED16(s1, fadd_op)
    DPP_RED16(s2, fadd_op)
    if (l15 == 15) { sSum[m] = s1; sSq[m] = s2; }
  }
  __syncthreads();
  if (t < 64) {
    partials[(size_t)blockIdx.x * 128 + t] = sSum[t];
    partials[(size_t)blockIdx.x * 128 + 64 + t] = sSq[t];
  }
}

// ------------------------------------------------------------------
// conv2 via MFMA bf16, 2 s per block (W2 staged once per 2 outputs).
// Wave wv: A rows wv*32..+31 (2 frags); 4 B tiles (2 s x 2 halves);
// 16 mfma. Epilogue: +bias, per-s max/min pool + combined sum/sumsq.
// ------------------------------------------------------------------
__global__ __launch_bounds__(256) void conv2_mfma_kernel(
    const float* __restrict__ y1, const float* __restrict__ W2,
    const float* __restrict__ b2, const float* __restrict__ scaleA,
    const float* __restrict__ shiftA, float* __restrict__ pmax,
    float* __restrict__ pmin, float* __restrict__ partials) {
  __shared__ __align__(16) short sW2[128 * 72];  // 18432 B, [o][c] pitch 72
  __shared__ __align__(16) short sXb[64 * 72];   // 9216 B,  2 s x [n][c]
  __shared__ float sScale[64], sShift[64], sBias[128];
  __shared__ float sSum[128], sSq[128];
  __shared__ float sMax[2][128], sMin[2][128];

  const int t = threadIdx.x;
  const int pair0 = blockIdx.x * 2;
  const int lane = t & 63;
  const int wv = t >> 6;
  const int quad = lane >> 4;
  const int l15 = lane & 15;

  if (t < 64) { sScale[t] = scaleA[t]; sShift[t] = shiftA[t]; }
  if (t < 128) sBias[t] = b2[t];
  for (int f = t; f < 8192; f += 256) {
    int o = f >> 6, c = f & 63;
    sW2[o * 72 + c] = f2bf(W2[f]);
  }
  for (int f = t; f < 4096; f += 256) {
    int si = f >> 11;
    int rmd = f & 2047;
    int o = rmd >> 5, k = rmd & 31;
    float v = y1[(size_t)(pair0 + si) * 2048 + rmd];
    v = v * sScale[o] + sShift[o];
    v = fmaxf(v, 0.f);
    sXb[(si * 32 + k) * 72 + o] = f2bf(v);
  }
  __syncthreads();

  f32x4 acc[2][4];
#pragma unroll
  for (int i = 0; i < 2; ++i)
#pragma unroll
    for (int ti = 0; ti < 4; ++ti) acc[i][ti] = (f32x4){0.f, 0.f, 0.f, 0.f};
#pragma unroll
  for (int kh = 0; kh < 2; ++kh) {
    const int kc = kh * 32 + quad * 8;
    bf16x8 A0 = *(const bf16x8*)(sW2 + (wv * 32 + l15) * 72 + kc);
    bf16x8 A1 = *(const bf16x8*)(sW2 + (wv * 32 + 16 + l15) * 72 + kc);
#pragma unroll
    for (int ti = 0; ti < 4; ++ti) {
      bf16x8 B = *(const bf16x8*)(sXb + (ti * 16 + l15) * 72 + kc);
      acc[0][ti] = __builtin_amdgcn_mfma_f32_16x16x32_bf16(A0, B, acc[0][ti], 0, 0, 0);
      acc[1][ti] = __builtin_amdgcn_mfma_f32_16x16x32_bf16(A1, B, acc[1][ti], 0, 0, 0);
    }
  }

#pragma unroll
  for (int i = 0; i < 2; ++i) {
#pragma unroll
    for (int reg = 0; reg < 4; ++reg) {
      const int m = wv * 32 + i * 16 + quad * 4 + reg;
      const float bb = sBias[m];
      float v0 = acc[i][0][reg] + bb;  // s0 cols 0-15
      float v1 = acc[i][1][reg] + bb;  // s0 cols 16-31
      float v2 = acc[i][2][reg] + bb;  // s1 cols 0-15
      float v3 = acc[i][3][reg] + bb;  // s1 cols 16-31
      float s1 = (v0 + v1) + (v2 + v3);
      float s2 = (v0 * v0 + v1 * v1) + (v2 * v2 + v3 * v3);
      float mx0 = fmaxf(v0, v1), mn0 = fminf(v0, v1);
      float mx1 = fmaxf(v2, v3), mn1 = fminf(v2, v3);
      DPP_RED16(s1, fadd_op)
      DPP_RED16(s2, fadd_op)
      DPP_RED16(mx0, fmaxf)
      DPP_RED16(mn0, fminf)
      DPP_RED16(mx1, fmaxf)
      DPP_RED16(mn1, fminf)
      if (l15 == 15) {
        sSum[m] = s1;
        sSq[m] = s2;
        sMax[0][m] = mx0;
        sMin[0][m] = mn0;
        sMax[1][m] = mx1;
        sMin[1][m] = mn1;
      }
    }
  }
  __syncthreads();
  if (t < 128) {
    partials[(size_t)blockIdx.x * 256 + t] = sSum[t];
    partials[(size_t)blockIdx.x * 256 + 128 + t] = sSq[t];
    pmax[(size_t)pair0 * 128 + t] = sMax[0][t];
    pmin[(size_t)pair0 * 128 + t] = sMin[0][t];
    pmax[(size_t)(pair0 + 1) * 128 + t] = sMax[1][t];
    pmin[(size_t)(pair0 + 1) * 128 + t] = sMin[1][t];
  }
}

// one block per channel: f64 reduce -> fused scale/shift for next layer
template <int COUT>
__global__ __launch_bounds__(256) void stats_kernel(const float* __restrict__ partials,
                                                    int nblocks,
                                                    const float* __restrict__ gA,
                                                    const float* __restrict__ btA,
                                                    float* __restrict__ scaleA,
                                                    float* __restrict__ shiftA) {
  const int o = blockIdx.x;
  const int t = threadIdx.x;
  double s1 = 0.0, s2 = 0.0;
  for (int blk = t; blk < nblocks; blk += 256) {
    s1 += (double)partials[(size_t)blk * (COUT * 2) + o];
    s2 += (double)partials[(size_t)blk * (COUT * 2) + COUT + o];
  }
  __shared__ double r1[256], r2[256];
  r1[t] = s1; r2[t] = s2;
  __syncthreads();
  for (int st = 128; st > 0; st >>= 1) {
    if (t < st) { r1[t] += r1[t + st]; r2[t] += r2[t + st]; }
    __syncthreads();
  }
  if (t == 0) {
    const double Nr = 262144.0;  // B*K*S
    double mean = r1[0] / Nr;
    double var = r2[0] / Nr - mean * mean;
    double rstd = 1.0 / sqrt(var + 1e-5);
    double sc = rstd * (double)gA[o];
    scaleA[o] = (float)sc;
    shiftA[o] = (float)((double)btA[o] - mean * sc);
  }
}

// layer-2 stats + final normalize fused: one block per channel (128).
__global__ __launch_bounds__(256) void stats_final_kernel(
    const float* __restrict__ partials, int nblocks,
    const float* __restrict__ pmax, const float* __restrict__ pmin,
    const float* __restrict__ gA, const float* __restrict__ btA,
    float* __restrict__ out) {
  const int o = blockIdx.x;
  const int t = threadIdx.x;
  double s1 = 0.0, s2 = 0.0;
  for (int blk = t; blk < nblocks; blk += 256) {
    s1 += (double)partials[(size_t)blk * 256 + o];
    s2 += (double)partials[(size_t)blk * 256 + 128 + o];
  }
  __shared__ double r1[256], r2[256];
  __shared__ float sMean, sRstd;
  r1[t] = s1; r2[t] = s2;
  __syncthreads();
  for (int st = 128; st > 0; st >>= 1) {
    if (t < st) { r1[t] += r1[t + st]; r2[t] += r2[t + st]; }
    __syncthreads();
  }
  if (t == 0) {
    const double Nr = 262144.0;
    double mean = r1[0] / Nr;
    double var = r2[0] / Nr - mean * mean;
    sMean = (float)mean;
    sRstd = (float)(1.0 / sqrt(var + 1e-5));
  }
  __syncthreads();
  const float mn = sMean, rs = sRstd, gg = gA[o], bb = btA[o];
  const float slope = rs * gg;
  const float* src = (slope >= 0.f) ? pmax : pmin;
  for (int i = t; i < NB * NS; i += 256) {
    int b = i >> 10;
    int s = i & 1023;
    float v = src[(size_t)i * 128 + o];
    float t1 = (v - mn) * rs;
    float t2 = t1 * gg + bb;
    out[(size_t)b * (128 * NS) + o * NS + s] = fmaxf(t2, 0.f);
  }
}

extern "C" void kernel_launch(void* const* d_in, const int* in_sizes, int n_in,
                              void* d_out, int out_size, void* d_ws, size_t ws_size,
                              hipStream_t stream) {
  (void)in_sizes; (void)n_in; (void)out_size; (void)ws_size;
  const float* xyz = (const float*)d_in[0];
  const float* points = (const float*)d_in[1];
  const float* W0 = (const float*)d_in[2];
  const float* b0 = (const float*)d_in[3];
  const float* g0 = (const float*)d_in[4];
  const float* bt0 = (const float*)d_in[5];
  const float* W1 = (const float*)d_in[6];
  const float* b1 = (const float*)d_in[7];
  const float* g1 = (const float*)d_in[8];
  const float* bt1 = (const float*)d_in[9];
  const float* W2 = (const float*)d_in[10];
  const float* b2 = (const float*)d_in[11];
  const float* g2 = (const float*)d_in[12];
  const float* bt2 = (const float*)d_in[13];
  float* out = (float*)d_out;

  float* ws = (float*)d_ws;
  size_t off = 0;
  float* newxyz = ws + off;  off += (size_t)NB * NS * 3;
  int* idx = (int*)(ws + off); off += (size_t)NB * NS * NK;
  float* P1 = ws + off;      off += (size_t)NB * NPTS * 64;
  float* y1 = ws + off;      off += (size_t)NB * NS * 64 * 32;
  float* partials = ws + off; off += (size_t)8192 * 256;
  float* scaleA = ws + off;  off += 128;
  float* shiftA = ws + off;  off += 128;
  float* pmaxb = ws + off;   off += (size_t)NB * NS * 128;
  float* pminb = ws + off;   off += (size_t)NB * NS * 128;

  // blocks 0-7: fps (8 CUs); blocks 8-519: pgemm hidden on idle CUs
  fps_pgemm_kernel<<<520, 512, 0, stream>>>(xyz, out, newxyz, points, W0, b0, P1);
  query_gstats_kernel<<<2048, 256, 0, stream>>>(xyz, newxyz, P1, W0, idx, partials);
  stats_kernel<64><<<64, 256, 0, stream>>>(partials, 2048, g0, bt0, scaleA, shiftA);
  conv1_mfma_kernel<<<4096, 256, 0, stream>>>(xyz, P1, idx, newxyz, W0, W1, b1,
                                              scaleA, shiftA, y1, partials);
  stats_kernel<64><<<64, 256, 0, stream>>>(partials, 4096, g1, bt1, scaleA, shiftA);
  conv2_mfma_kernel<<<4096, 256, 0, stream>>>(y1, W2, b2, scaleA, shiftA,
                                              pmaxb, pminb, partials);
  stats_final_kernel<<<128, 256, 0, stream>>>(partials, 4096, pmaxb, pminb,
                                              g2, bt2, out + NB * NS * 3);
}

// Round 16
// 951.227 us; speedup vs baseline: 1.8491x; 1.0189x over previous
//
#include <hip/hip_runtime.h>
#include <cstddef>
#include <cstdint>

#define NB 8
#define NPTS 4096
#define NS 1024
#define NK 32
#define ND 64

typedef __attribute__((ext_vector_type(8))) short bf16x8;  // 8 bf16 (4 VGPRs)
typedef __attribute__((ext_vector_type(4))) float f32x4;

__device__ __forceinline__ short f2bf(float f) {  // RNE f32->bf16
  unsigned u = __float_as_uint(f);
  u += 0x7FFF + ((u >> 16) & 1);
  return (short)(u >> 16);
}

// ------------------------------------------------------------------
// fps+pgemm hetero-grid kernel (R12 verbatim — fps floored at ~700us).
// ------------------------------------------------------------------
#define DPP_IMAX(v, ctrl)                                                     \
  {                                                                           \
    int _o = __builtin_amdgcn_update_dpp(v, v, ctrl, 0xf, 0xf, false);        \
    v = (_o > v) ? _o : v;                                                    \
  }

#define DPP_U64MAX(hi, lo, ctrl)                                              \
  {                                                                           \
    unsigned _nh = (unsigned)__builtin_amdgcn_update_dpp((int)(hi), (int)(hi),\
                                                         ctrl, 0xf, 0xf, false);\
    unsigned _nl = (unsigned)__builtin_amdgcn_update_dpp((int)(lo), (int)(lo),\
                                                         ctrl, 0xf, 0xf, false);\
    bool _gt = (_nh > (hi)) || (_nh == (hi) && _nl > (lo));                   \
    hi = _gt ? _nh : (hi);                                                    \
    lo = _gt ? _nl : (lo);                                                    \
  }

// 16-lane reductions (only lane 15 mod 16 result is consumed)
#define DPP_RED16(v, OP)                                                      \
  {                                                                           \
    int _i;                                                                   \
    _i = __builtin_amdgcn_update_dpp(__float_as_int(v), __float_as_int(v), 0x111, 0xf, 0xf, false); \
    v = OP(v, __int_as_float(_i));                                            \
    _i = __builtin_amdgcn_update_dpp(__float_as_int(v), __float_as_int(v), 0x112, 0xf, 0xf, false); \
    v = OP(v, __int_as_float(_i));                                            \
    _i = __builtin_amdgcn_update_dpp(__float_as_int(v), __float_as_int(v), 0x114, 0xf, 0xf, false); \
    v = OP(v, __int_as_float(_i));                                            \
    _i = __builtin_amdgcn_update_dpp(__float_as_int(v), __float_as_int(v), 0x118, 0xf, 0xf, false); \
    v = OP(v, __int_as_float(_i));                                            \
  }

__device__ __forceinline__ float fadd_op(float a, float b) { return a + b; }

__global__ __launch_bounds__(512) void fps_pgemm_kernel(
    const float* __restrict__ xyz, float* __restrict__ out_newxyz,
    float* __restrict__ ws_newxyz, const float* __restrict__ points,
    const float* __restrict__ W0, const float* __restrict__ b0g,
    float* __restrict__ P1) {
  __shared__ __align__(16) char smem[53376];
  const int t = threadIdx.x;

  if (blockIdx.x < 8) {
    // ---------------- FPS ----------------
    float* sXYZ = (float*)smem;                                    // 49152 B
    unsigned long long(*sRed)[8] =
        (unsigned long long(*)[8])(smem + 49152);                  // 128 B
    int* sWidx = (int*)(smem + 49280);                             // 4096 B
    const int b = blockIdx.x;
    const int wave = t >> 6;
    const int lane = t & 63;
    const float* xb = xyz + (size_t)b * 3 * NPTS;

    for (int i = t; i < NPTS; i += 512) {
      sXYZ[i * 3 + 0] = xb[i];
      sXYZ[i * 3 + 1] = xb[NPTS + i];
      sXYZ[i * 3 + 2] = xb[2 * NPTS + i];
    }
    if (t == 0) sWidx[0] = 0;

    float px[8], py[8], pz[8], dist[8];
    {
      float4 a0 = ((const float4*)xb)[2 * t];
      float4 a1 = ((const float4*)xb)[2 * t + 1];
      float4 b0v = ((const float4*)(xb + NPTS))[2 * t];
      float4 b1v = ((const float4*)(xb + NPTS))[2 * t + 1];
      float4 c0 = ((const float4*)(xb + 2 * NPTS))[2 * t];
      float4 c1 = ((const float4*)(xb + 2 * NPTS))[2 * t + 1];
      px[0] = a0.x; px[1] = a0.y; px[2] = a0.z; px[3] = a0.w;
      px[4] = a1.x; px[5] = a1.y; px[6] = a1.z; px[7] = a1.w;
      py[0] = b0v.x; py[1] = b0v.y; py[2] = b0v.z; py[3] = b0v.w;
      py[4] = b1v.x; py[5] = b1v.y; py[6] = b1v.z; py[7] = b1v.w;
      pz[0] = c0.x; pz[1] = c0.y; pz[2] = c0.z; pz[3] = c0.w;
      pz[4] = c1.x; pz[5] = c1.y; pz[6] = c1.z; pz[7] = c1.w;
    }
#pragma unroll
    for (int j = 0; j < 8; ++j) dist[j] = 1e10f;

    float cx = xb[0], cy = xb[NPTS], cz = xb[2 * NPTS];  // centroid 0

    for (int s = 0; s < NS; ++s) {
#pragma unroll
      for (int j = 0; j < 8; ++j) {
        float dx = __fadd_rn(px[j], -cx);
        float dy = __fadd_rn(py[j], -cy);
        float dz = __fadd_rn(pz[j], -cz);
        float d = __fadd_rn(__fadd_rn(__fmul_rn(dx, dx), __fmul_rn(dy, dy)),
                            __fmul_rn(dz, dz));
        dist[j] = fminf(dist[j], d);
      }
      float m = fmaxf(fmaxf(fmaxf(dist[0], dist[1]), fmaxf(dist[2], dist[3])),
                      fmaxf(fmaxf(dist[4], dist[5]), fmaxf(dist[6], dist[7])));
      int v = __float_as_int(m);
      DPP_IMAX(v, 0x111)
      DPP_IMAX(v, 0x112)
      DPP_IMAX(v, 0x114)
      DPP_IMAX(v, 0x118)
      DPP_IMAX(v, 0x142)
      DPP_IMAX(v, 0x143)
      const int wm_i = __builtin_amdgcn_readlane(v, 63);
      const float wm = __int_as_float(wm_i);
      unsigned long long claim = __ballot(m == wm);
      int firstlane = __ffsll(claim) - 1;
      if (lane == firstlane) {
        int j = 7;
#pragma unroll
        for (int jj = 6; jj >= 0; --jj)
          if (dist[jj] == wm) j = jj;
        unsigned widx = (unsigned)(t * 8 + j);
        sRed[s & 1][wave] = ((unsigned long long)(unsigned)wm_i << 32) |
                            (unsigned long long)(0xFFFFFFFFu - widx);
      }
      __syncthreads();
      unsigned long long k = sRed[s & 1][lane & 7];
      unsigned h2 = (unsigned)(k >> 32), l2 = (unsigned)k;
      DPP_U64MAX(h2, l2, 0x111)
      DPP_U64MAX(h2, l2, 0x112)
      DPP_U64MAX(h2, l2, 0x114)
      const unsigned gl = (unsigned)__builtin_amdgcn_readlane((int)l2, 7);
      const int widx = (int)(0xFFFFFFFFu - gl);
      cx = sXYZ[widx * 3 + 0];
      cy = sXYZ[widx * 3 + 1];
      cz = sXYZ[widx * 3 + 2];
      if (t == 0 && s < NS - 1) sWidx[s + 1] = widx;
    }
    __syncthreads();
    for (int s2 = t; s2 < NS; s2 += 512) {
      int w = sWidx[s2];
      float x = sXYZ[w * 3 + 0], y = sXYZ[w * 3 + 1], z = sXYZ[w * 3 + 2];
      out_newxyz[b * 3 * NS + s2] = x;
      out_newxyz[b * 3 * NS + NS + s2] = y;
      out_newxyz[b * 3 * NS + 2 * NS + s2] = z;
      ws_newxyz[((b << 10) + s2) * 3 + 0] = x;
      ws_newxyz[((b << 10) + s2) * 3 + 1] = y;
      ws_newxyz[((b << 10) + s2) * 3 + 2] = z;
    }
  } else {
    // ---------------- pgemm: P1[b][n][o] = points·W0[:,3:] + b0 ----------
    float* sP = (float*)smem;            // 16384 B  [c][n]
    float* sW = (float*)(smem + 16384);  // 17408 B  [c][o] pitch 68
    float* sB = (float*)(smem + 33792);  // 256 B
    const int blk = blockIdx.x - 8;      // 0..511
    const int bb = blk >> 6;
    const int n0 = (blk & 63) * 64;
    const float* pb = points + (size_t)bb * ND * NPTS;
    for (int f = t; f < 4096; f += 512) {
      int c = f >> 6, n = f & 63;
      sP[f] = pb[c * NPTS + n0 + n];
    }
    for (int f = t; f < 4096; f += 512) {
      int c = f >> 6, o = f & 63;
      sW[c * 68 + o] = W0[o * 67 + 3 + c];
    }
    if (t < 64) sB[t] = b0g[t];
    __syncthreads();
    if (t < 256) {
      const int nl = (t & 15) * 4;
      const int ol = (t >> 4) * 4;
      float acc[4][4];
#pragma unroll
      for (int i = 0; i < 4; ++i)
#pragma unroll
        for (int j = 0; j < 4; ++j) acc[i][j] = 0.f;
#pragma unroll 4
      for (int c = 0; c < 64; ++c) {
        float4 xv = *(const float4*)(sP + c * 64 + nl);
        float4 wv = *(const float4*)(sW + c * 68 + ol);
        float xa[4] = {xv.x, xv.y, xv.z, xv.w};
        float wa[4] = {wv.x, wv.y, wv.z, wv.w};
#pragma unroll
        for (int i = 0; i < 4; ++i)
#pragma unroll
          for (int j = 0; j < 4; ++j) acc[i][j] += xa[i] * wa[j];
      }
#pragma unroll
      for (int i = 0; i < 4; ++i) {
        float4 v = make_float4(acc[i][0] + sB[ol + 0], acc[i][1] + sB[ol + 1],
                               acc[i][2] + sB[ol + 2], acc[i][3] + sB[ol + 3]);
        *(float4*)(P1 + ((size_t)(bb << 12) + n0 + nl + i) * 64 + ol) = v;
      }
    }
  }
}

// ------------------------------------------------------------------
// Ball query + layer-0 gather stats fused (R12 verbatim)
// ------------------------------------------------------------------
__global__ __launch_bounds__(256) void query_gstats_kernel(
    const float* __restrict__ xyz, const float* __restrict__ ws_newxyz,
    const float* __restrict__ P1, const float* __restrict__ W0,
    int* __restrict__ idx_ws, float* __restrict__ partials) {
  const int w = threadIdx.x >> 6;
  const int lane = threadIdx.x & 63;
  const int p = blockIdx.x * 4 + w;  // 8192 pairs
  const int b = p >> 10;
  __shared__ int sIdx[4][32];
  __shared__ float sWS[4][64];
  __shared__ float sWQ[4][64];
  const float* xb = xyz + (size_t)b * 3 * NPTS;
  const float cx = ws_newxyz[p * 3 + 0];
  const float cy = ws_newxyz[p * 3 + 1];
  const float cz = ws_newxyz[p * 3 + 2];
  const float ss = __fadd_rn(__fadd_rn(__fmul_rn(cx, cx), __fmul_rn(cy, cy)), __fmul_rn(cz, cz));
  const float r2 = (float)(0.4 * 0.4);
  int cnt = 0;
  for (int ci = 0; ci < 64 && cnt < 32; ++ci) {
    int n = ci * 64 + lane;
    float x = xb[n], y = xb[NPTS + n], z = xb[2 * NPTS + n];
    float dot = __fadd_rn(__fadd_rn(__fmul_rn(cx, x), __fmul_rn(cy, y)), __fmul_rn(cz, z));
    float dd = __fadd_rn(__fadd_rn(__fmul_rn(x, x), __fmul_rn(y, y)), __fmul_rn(z, z));
    float d = __fmul_rn(-2.0f, dot);
    d = __fadd_rn(d, ss);
    d = __fadd_rn(d, dd);
    d = fmaxf(d, 1e-12f);  // clip
    bool inc = (d <= r2);
    unsigned long long m = __ballot(inc);
    int slot = cnt + (int)__popcll(m & ((1ull << lane) - 1ull));
    if (inc && slot < 32) sIdx[w][slot] = n;
    cnt += (int)__popcll(m);
  }
  if (lane < 32) {
    int v;
    if (lane < cnt) v = sIdx[w][lane];
    else v = (cnt > 0) ? sIdx[w][0] : 0;
    idx_ws[p * 32 + lane] = v;
    sIdx[w][lane] = v;
  }
  const float wx = W0[lane * 67 + 0];
  const float wy = W0[lane * 67 + 1];
  const float wz = W0[lane * 67 + 2];
  float ssum = 0.f, ssq = 0.f;
  for (int r = 0; r < 32; ++r) {
    const int n = sIdx[w][r];
    float P1v = P1[((size_t)(b << 12) + n) * 64 + lane];
    float dx = __fadd_rn(xb[n], -cx);
    float dy = __fadd_rn(xb[NPTS + n], -cy);
    float dz = __fadd_rn(xb[2 * NPTS + n], -cz);
    float y = P1v + (dx * wx + dy * wy + dz * wz);
    ssum += y;
    ssq += y * y;
  }
  sWS[w][lane] = ssum;
  sWQ[w][lane] = ssq;
  __syncthreads();
  const int t = threadIdx.x;
  if (t < 64) {
    float s1 = sWS[0][t] + sWS[1][t] + sWS[2][t] + sWS[3][t];
    float s2 = sWQ[0][t] + sWQ[1][t] + sWQ[2][t] + sWQ[3][t];
    partials[(size_t)blockIdx.x * 128 + t] = s1;
    partials[(size_t)blockIdx.x * 128 + 64 + t] = s2;
  }
}

// ------------------------------------------------------------------
// conv1 via MFMA bf16, 4 s per block (grid 2048). Gather-recompute
// staging writes B-layout sXb[r=(sl*32+k)][c] bf16 directly. Wave wv:
// A rows wv*16..+15; 8 B tiles (4 s x 2 halves); 16 mfma. Epilogue:
// +bias, y1 fp32 write, layer-1 sum/sumsq via DPP16, direct partial
// writes from lane15-of-16 (C: col=lane&15, row=quad*4+reg).
// ------------------------------------------------------------------
__global__ __launch_bounds__(256) void conv1_mfma_kernel(
    const float* __restrict__ xyz, const float* __restrict__ P1,
    const int* __restrict__ idx_ws, const float* __restrict__ cen_ws,
    const float* __restrict__ W0, const float* __restrict__ W1,
    const float* __restrict__ b1, const float* __restrict__ scaleA,
    const float* __restrict__ shiftA, float* __restrict__ y1,
    float* __restrict__ partials) {
  __shared__ __align__(16) short sW1b[64 * 72];   // 9216 B
  __shared__ __align__(16) short sXb[128 * 72];   // 18432 B
  __shared__ int sIdx[128];
  __shared__ float sCen[4 * 4];
  __shared__ float sBias[64];

  const int t = threadIdx.x;
  const int wv = t >> 6, lane = t & 63;
  const int quad = lane >> 4, l15 = lane & 15;
  const int pair0 = blockIdx.x * 4;
  const int b = pair0 >> 10;

  for (int f = t; f < 4096; f += 256) sW1b[(f >> 6) * 72 + (f & 63)] = f2bf(W1[f]);
  if (t < 64) sBias[t] = b1[t];
  if (t < 128) sIdx[t] = idx_ws[pair0 * 32 + t];
  if (t < 12) sCen[(t / 3) * 4 + (t % 3)] = cen_ws[pair0 * 3 + t];
  const float wx = W0[lane * 67 + 0];
  const float wy = W0[lane * 67 + 1];
  const float wz = W0[lane * 67 + 2];
  const float sc = scaleA[lane];
  const float sh = shiftA[lane];
  __syncthreads();
  const float* xb = xyz + (size_t)b * 3 * NPTS;
  for (int r = wv; r < 128; r += 4) {
    const int sl = r >> 5;
    const int n = sIdx[r];
    float P1v = P1[((size_t)(b << 12) + n) * 64 + lane];
    float dx = __fadd_rn(xb[n], -sCen[sl * 4 + 0]);
    float dy = __fadd_rn(xb[NPTS + n], -sCen[sl * 4 + 1]);
    float dz = __fadd_rn(xb[2 * NPTS + n], -sCen[sl * 4 + 2]);
    float y0 = P1v + (dx * wx + dy * wy + dz * wz);
    sXb[r * 72 + lane] = f2bf(fmaxf(y0 * sc + sh, 0.f));
  }
  __syncthreads();

  f32x4 acc[8];
#pragma unroll
  for (int i = 0; i < 8; ++i) acc[i] = (f32x4){0.f, 0.f, 0.f, 0.f};
#pragma unroll
  for (int kh = 0; kh < 2; ++kh) {
    const int kc = kh * 32 + quad * 8;
    bf16x8 A = *(const bf16x8*)(sW1b + (wv * 16 + l15) * 72 + kc);
#pragma unroll
    for (int ti = 0; ti < 8; ++ti) {
      bf16x8 B = *(const bf16x8*)(sXb + (ti * 16 + l15) * 72 + kc);
      acc[ti] = __builtin_amdgcn_mfma_f32_16x16x32_bf16(A, B, acc[ti], 0, 0, 0);
    }
  }

#pragma unroll
  for (int reg = 0; reg < 4; ++reg) {
    const int m = wv * 16 + quad * 4 + reg;
    const float bb = sBias[m];
    float v[8];
#pragma unroll
    for (int ti = 0; ti < 8; ++ti) {
      v[ti] = acc[ti][reg] + bb;
      y1[(size_t)(pair0 + (ti >> 1)) * 2048 + m * 32 + (ti & 1) * 16 + l15] = v[ti];
    }
    float s1 = ((v[0] + v[1]) + (v[2] + v[3])) + ((v[4] + v[5]) + (v[6] + v[7]));
    float s2 = ((v[0] * v[0] + v[1] * v[1]) + (v[2] * v[2] + v[3] * v[3])) +
               ((v[4] * v[4] + v[5] * v[5]) + (v[6] * v[6] + v[7] * v[7]));
    DPP_RED16(s1, fadd_op)
    DPP_RED16(s2, fadd_op)
    if (l15 == 15) {
      partials[(size_t)blockIdx.x * 128 + m] = s1;
      partials[(size_t)blockIdx.x * 128 + 64 + m] = s2;
    }
  }
}

// ------------------------------------------------------------------
// conv2 via MFMA bf16, 4 s per block (grid 2048; W2 staged once per 4
// outputs). Wave wv: A rows wv*32..+31 (2 frags); 8 B tiles; 32 mfma.
// Epilogue: +bias, per-s max/min pool + sum/sumsq via DPP16; pooled
// values written TRANSPOSED pmaxT/pminT[c][p] (4 contiguous floats per
// m) so stats_final reads coalesced rows.
// ------------------------------------------------------------------
__global__ __launch_bounds__(256) void conv2_mfma_kernel(
    const float* __restrict__ y1, const float* __restrict__ W2,
    const float* __restrict__ b2, const float* __restrict__ scaleA,
    const float* __restrict__ shiftA, float* __restrict__ pmaxT,
    float* __restrict__ pminT, float* __restrict__ partials) {
  __shared__ __align__(16) short sW2[128 * 72];  // 18432 B, [o][c] pitch 72
  __shared__ __align__(16) short sXb[128 * 72];  // 18432 B, 4 s x [n][c]
  __shared__ float sScale[64], sShift[64], sBias[128];

  const int t = threadIdx.x;
  const int pair0 = blockIdx.x * 4;
  const int lane = t & 63;
  const int wv = t >> 6;
  const int quad = lane >> 4;
  const int l15 = lane & 15;

  if (t < 64) { sScale[t] = scaleA[t]; sShift[t] = shiftA[t]; }
  if (t < 128) sBias[t] = b2[t];
  for (int f = t; f < 8192; f += 256) {
    int o = f >> 6, c = f & 63;
    sW2[o * 72 + c] = f2bf(W2[f]);
  }
  for (int f = t; f < 8192; f += 256) {
    int si = f >> 11;
    int rmd = f & 2047;
    int o = rmd >> 5, k = rmd & 31;
    float v = y1[(size_t)(pair0 + si) * 2048 + rmd];
    v = v * sScale[o] + sShift[o];
    v = fmaxf(v, 0.f);
    sXb[(si * 32 + k) * 72 + o] = f2bf(v);
  }
  __syncthreads();

  f32x4 acc[2][8];
#pragma unroll
  for (int i = 0; i < 2; ++i)
#pragma unroll
    for (int ti = 0; ti < 8; ++ti) acc[i][ti] = (f32x4){0.f, 0.f, 0.f, 0.f};
#pragma unroll
  for (int kh = 0; kh < 2; ++kh) {
    const int kc = kh * 32 + quad * 8;
    bf16x8 A0 = *(const bf16x8*)(sW2 + (wv * 32 + l15) * 72 + kc);
    bf16x8 A1 = *(const bf16x8*)(sW2 + (wv * 32 + 16 + l15) * 72 + kc);
#pragma unroll
    for (int ti = 0; ti < 8; ++ti) {
      bf16x8 B = *(const bf16x8*)(sXb + (ti * 16 + l15) * 72 + kc);
      acc[0][ti] = __builtin_amdgcn_mfma_f32_16x16x32_bf16(A0, B, acc[0][ti], 0, 0, 0);
      acc[1][ti] = __builtin_amdgcn_mfma_f32_16x16x32_bf16(A1, B, acc[1][ti], 0, 0, 0);
    }
  }

#pragma unroll
  for (int i = 0; i < 2; ++i) {
#pragma unroll
    for (int reg = 0; reg < 4; ++reg) {
      const int m = wv * 32 + i * 16 + quad * 4 + reg;
      const float bb = sBias[m];
      float v[8];
#pragma unroll
      for (int ti = 0; ti < 8; ++ti) v[ti] = acc[i][ti][reg] + bb;
      float s1 = ((v[0] + v[1]) + (v[2] + v[3])) + ((v[4] + v[5]) + (v[6] + v[7]));
      float s2 = ((v[0] * v[0] + v[1] * v[1]) + (v[2] * v[2] + v[3] * v[3])) +
                 ((v[4] * v[4] + v[5] * v[5]) + (v[6] * v[6] + v[7] * v[7]));
      DPP_RED16(s1, fadd_op)
      DPP_RED16(s2, fadd_op)
      if (l15 == 15) {
        partials[(size_t)blockIdx.x * 256 + m] = s1;
        partials[(size_t)blockIdx.x * 256 + 128 + m] = s2;
      }
#pragma unroll
      for (int si = 0; si < 4; ++si) {
        float mx = fmaxf(v[2 * si], v[2 * si + 1]);
        float mn = fminf(v[2 * si], v[2 * si + 1]);
        DPP_RED16(mx, fmaxf)
        DPP_RED16(mn, fminf)
        if (l15 == 15) {
          pmaxT[(size_t)m * 8192 + pair0 + si] = mx;
          pminT[(size_t)m * 8192 + pair0 + si] = mn;
        }
      }
    }
  }
}

// one block per channel: f64 reduce -> fused scale/shift for next layer
template <int COUT>
__global__ __launch_bounds__(256) void stats_kernel(const float* __restrict__ partials,
                                                    int nblocks,
                                                    const float* __restrict__ gA,
                                                    const float* __restrict__ btA,
                                                    float* __restrict__ scaleA,
                                                    float* __restrict__ shiftA) {
  const int o = blockIdx.x;
  const int t = threadIdx.x;
  double s1 = 0.0, s2 = 0.0;
  for (int blk = t; blk < nblocks; blk += 256) {
    s1 += (double)partials[(size_t)blk * (COUT * 2) + o];
    s2 += (double)partials[(size_t)blk * (COUT * 2) + COUT + o];
  }
  __shared__ double r1[256], r2[256];
  r1[t] = s1; r2[t] = s2;
  __syncthreads();
  for (int st = 128; st > 0; st >>= 1) {
    if (t < st) { r1[t] += r1[t + st]; r2[t] += r2[t + st]; }
    __syncthreads();
  }
  if (t == 0) {
    const double Nr = 262144.0;  // B*K*S
    double mean = r1[0] / Nr;
    double var = r2[0] / Nr - mean * mean;
    double rstd = 1.0 / sqrt(var + 1e-5);
    double sc = rstd * (double)gA[o];
    scaleA[o] = (float)sc;
    shiftA[o] = (float)((double)btA[o] - mean * sc);
  }
}

// layer-2 stats + final normalize fused: one block per channel (128).
// pmaxT/pminT are [c][p] -> fully coalesced row reads.
__global__ __launch_bounds__(256) void stats_final_kernel(
    const float* __restrict__ partials, int nblocks,
    const float* __restrict__ pmaxT, const float* __restrict__ pminT,
    const float* __restrict__ gA, const float* __restrict__ btA,
    float* __restrict__ out) {
  const int o = blockIdx.x;
  const int t = threadIdx.x;
  double s1 = 0.0, s2 = 0.0;
  for (int blk = t; blk < nblocks; blk += 256) {
    s1 += (double)partials[(size_t)blk * 256 + o];
    s2 += (double)partials[(size_t)blk * 256 + 128 + o];
  }
  __shared__ double r1[256], r2[256];
  __shared__ float sMean, sRstd;
  r1[t] = s1; r2[t] = s2;
  __syncthreads();
  for (int st = 128; st > 0; st >>= 1) {
    if (t < st) { r1[t] += r1[t + st]; r2[t] += r2[t + st]; }
    __syncthreads();
  }
  if (t == 0) {
    const double Nr = 262144.0;
    double mean = r1[0] / Nr;
    double var = r2[0] / Nr - mean * mean;
    sMean = (float)mean;
    sRstd = (float)(1.0 / sqrt(var + 1e-5));
  }
  __syncthreads();
  const float mn = sMean, rs = sRstd, gg = gA[o], bb = btA[o];
  const float slope = rs * gg;
  const float* src = (slope >= 0.f) ? pmaxT : pminT;
  for (int i = t; i < NB * NS; i += 256) {
    int b = i >> 10;
    int s = i & 1023;
    float v = src[(size_t)o * 8192 + i];
    float t1 = (v - mn) * rs;
    float t2 = t1 * gg + bb;
    out[(size_t)b * (128 * NS) + o * NS + s] = fmaxf(t2, 0.f);
  }
}

extern "C" void kernel_launch(void* const* d_in, const int* in_sizes, int n_in,
                              void* d_out, int out_size, void* d_ws, size_t ws_size,
                              hipStream_t stream) {
  (void)in_sizes; (void)n_in; (void)out_size; (void)ws_size;
  const float* xyz = (const float*)d_in[0];
  const float* points = (const float*)d_in[1];
  const float* W0 = (const float*)d_in[2];
  const float* b0 = (const float*)d_in[3];
  const float* g0 = (const float*)d_in[4];
  const float* bt0 = (const float*)d_in[5];
  const float* W1 = (const float*)d_in[6];
  const float* b1 = (const float*)d_in[7];
  const float* g1 = (const float*)d_in[8];
  const float* bt1 = (const float*)d_in[9];
  const float* W2 = (const float*)d_in[10];
  const float* b2 = (const float*)d_in[11];
  const float* g2 = (const float*)d_in[12];
  const float* bt2 = (const float*)d_in[13];
  float* out = (float*)d_out;

  float* ws = (float*)d_ws;
  size_t off = 0;
  float* newxyz = ws + off;  off += (size_t)NB * NS * 3;
  int* idx = (int*)(ws + off); off += (size_t)NB * NS * NK;
  float* P1 = ws + off;      off += (size_t)NB * NPTS * 64;
  float* y1 = ws + off;      off += (size_t)NB * NS * 64 * 32;
  float* partials = ws + off; off += (size_t)8192 * 256;
  float* scaleA = ws + off;  off += 128;
  float* shiftA = ws + off;  off += 128;
  float* pmaxT = ws + off;   off += (size_t)128 * NB * NS;
  float* pminT = ws + off;   off += (size_t)128 * NB * NS;

  // blocks 0-7: fps (8 CUs); blocks 8-519: pgemm hidden on idle CUs
  fps_pgemm_kernel<<<520, 512, 0, stream>>>(xyz, out, newxyz, points, W0, b0, P1);
  query_gstats_kernel<<<2048, 256, 0, stream>>>(xyz, newxyz, P1, W0, idx, partials);
  stats_kernel<64><<<64, 256, 0, stream>>>(partials, 2048, g0, bt0, scaleA, shiftA);
  conv1_mfma_kernel<<<2048, 256, 0, stream>>>(xyz, P1, idx, newxyz, W0, W1, b1,
                                              scaleA, shiftA, y1, partials);
  stats_kernel<64><<<64, 256, 0, stream>>>(partials, 2048, g1, bt1, scaleA, shiftA);
  conv2_mfma_kernel<<<2048, 256, 0, stream>>>(y1, W2, b2, scaleA, shiftA,
                                              pmaxT, pminT, partials);
  stats_final_kernel<<<128, 256, 0, stream>>>(partials, 2048, pmaxT, pminT,
                                              g2, bt2, out + NB * NS * 3);
}